// Round 1
// baseline (454.074 us; speedup 1.0000x reference)
//
#include <hip/hip_runtime.h>
#include <hip/hip_bf16.h>
#include <math.h>

typedef __bf16 bf16x8 __attribute__((ext_vector_type(8)));
typedef float f32x4 __attribute__((ext_vector_type(4)));
typedef unsigned int u32;
typedef u32 u32x4 __attribute__((ext_vector_type(4)));

// Problem constants: B=8, C=256, H=W=64, O=256, K=9, GN groups=32 (8 ch each)

__device__ inline u32 pack2bf16(float a, float b) {
  u32 ua = __float_as_uint(a);
  u32 ub = __float_as_uint(b);
  ua += 0x7fffu + ((ua >> 16) & 1u);   // RNE
  ub += 0x7fffu + ((ub >> 16) & 1u);
  return (ua >> 16) | (ub & 0xffff0000u);
}

// ---------------------------------------------------------------------------
// K0: prep — pack w_dcn into swizzled bf16 tiles, reorder w_off, zero offs/stats
// wT4: 36 tiles (ck-chunks of 64), each [256 o][64 kk] bf16 = 32KB, with
//      in-tile byte swizzle  lin ^ ((o&7)<<4)  so LDS-staged ds_read_b128 of
//      B-fragments is bank-conflict-free (pre-swizzled-global, linear LDS).
// w2:  [9][256][18] fp32  (k, c, o) for the offset conv (uniform scalar reads)
// ---------------------------------------------------------------------------
__global__ void prep(const float* __restrict__ w_dcn, const float* __restrict__ w_off,
                     unsigned short* __restrict__ wT4, float* __restrict__ w2,
                     float* __restrict__ offs, float* __restrict__ stats) {
  size_t id = (size_t)blockIdx.x * 256 + threadIdx.x;
  if (id < 589824) {               // 256 o * 2304 ck
    int o  = (int)(id / 2304);
    int ck = (int)(id % 2304);     // ck = k*256 + c
    int k = ck >> 8, c = ck & 255;
    float v = w_dcn[(size_t)(o * 256 + c) * 9 + k];
    u32 uv = __float_as_uint(v);
    uv += 0x7fffu + ((uv >> 16) & 1u);
    int tile = ck >> 6, kk = ck & 63;
    int lin = o * 128 + kk * 2;
    int swz = lin ^ ((o & 7) << 4);
    *(unsigned short*)((char*)wT4 + (size_t)tile * 32768 + swz) = (unsigned short)(uv >> 16);
  } else if (id < 631296) {        // 9*256*18 = 41472
    int r = (int)(id - 589824);    // r = (k*256+c)*18 + o
    int o = r % 18;
    int kc = r / 18;
    int c = kc & 255, k = kc >> 8;
    w2[r] = w_off[(size_t)(o * 256 + c) * 9 + k];
  } else if (id < 1221120) {       // zero offs: 8*4096*18 = 589824 floats
    offs[id - 631296] = 0.f;
  } else if (id < 1221632) {       // zero stats: 512 floats
    stats[id - 1221120] = 0.f;
  }
}

// ---------------------------------------------------------------------------
// K1: transpose x [B][C][H][W] -> xT [B][H][W][C]  (channels-last)
// grid: 8 b * 64 y * 4 cchunk = 2048 blocks of 256
// ---------------------------------------------------------------------------
__global__ __launch_bounds__(256) void transpose_x(const float* __restrict__ x,
                                                   float* __restrict__ xT) {
  __shared__ float tl[64][65];
  int bx = blockIdx.x;
  int b = bx >> 8;
  int y = (bx >> 2) & 63;
  int cb = (bx & 3) << 6;
  int t = threadIdx.x;
  int xi = t & 63, cr = t >> 6;
  size_t base = (((size_t)(b * 256 + cb) * 64 + y) << 6);
#pragma unroll
  for (int rep = 0; rep < 16; ++rep) {
    int cl = rep * 4 + cr;
    tl[cl][xi] = x[base + (size_t)cl * 4096 + xi];
  }
  __syncthreads();
  int xw = t >> 2, c4 = (t & 3) << 4;
  float* dst = xT + (((size_t)b * 4096) + y * 64 + xw) * 256 + cb + c4;
#pragma unroll
  for (int rep = 0; rep < 4; ++rep) {
    f32x4 v;
    v.x = tl[c4 + rep * 4 + 0][xw];
    v.y = tl[c4 + rep * 4 + 1][xw];
    v.z = tl[c4 + rep * 4 + 2][xw];
    v.w = tl[c4 + rep * 4 + 3][xw];
    *(f32x4*)(dst + rep * 4) = v;
  }
}

// ---------------------------------------------------------------------------
// K2: offset conv.  offs[b][px][18] += conv partials over a 64-channel chunk.
// grid: 8 b * 16 rowgroups * 4 cchunks = 512 blocks of 256 (1 px / thread)
// Weight reads are wave-uniform -> scalar loads.
// ---------------------------------------------------------------------------
__global__ __launch_bounds__(256) void conv_offset(const float* __restrict__ xT,
                                                   const float* __restrict__ w2,
                                                   float* __restrict__ offs) {
  int bx = blockIdx.x;
  int b = bx >> 6;
  int rg = (bx >> 2) & 15;
  int cchunk = bx & 3;
  int t = threadIdx.x;
  int pxg = rg * 256 + t;
  int yy = pxg >> 6, xx = pxg & 63;
  int cbase = cchunk << 6;
  float acc[18];
#pragma unroll
  for (int o = 0; o < 18; ++o) acc[o] = 0.f;
  const float* xb = xT + ((size_t)b << 12) * 256;
#pragma unroll
  for (int ky = 0; ky < 3; ++ky) {
    int ys = yy - 1 + ky;
    if ((unsigned)ys >= 64u) continue;
#pragma unroll
    for (int kx = 0; kx < 3; ++kx) {
      int xs = xx - 1 + kx;
      if ((unsigned)xs >= 64u) continue;
      const float* xp = xb + ((ys << 6) + xs) * 256 + cbase;
      const float* wk = w2 + ((size_t)((ky * 3 + kx) * 256 + cbase)) * 18;
      for (int c4 = 0; c4 < 16; ++c4) {
        f32x4 xv = *(const f32x4*)(xp + c4 * 4);
#pragma unroll
        for (int cc = 0; cc < 4; ++cc) {
          const float* wp = wk + (c4 * 4 + cc) * 18;
#pragma unroll
          for (int o = 0; o < 18; ++o) acc[o] = fmaf(xv[cc], wp[o], acc[o]);
        }
      }
    }
  }
  float* op = offs + ((size_t)b * 4096 + pxg) * 18;
#pragma unroll
  for (int o = 0; o < 18; ++o) atomicAdd(op + o, acc[o]);
}

// ---------------------------------------------------------------------------
// K4: main fused kernel: bilinear sample -> bf16 MFMA GEMM -> GN partials + y
// block = 64 pixels x 256 O, 4 waves (wave w owns o in [w*64, w*64+64))
// grid = 8 b * 64 rowgroups = 512 blocks of 256
// ---------------------------------------------------------------------------
union SmemArena {
  struct {
    int poff[64][9][4];            // 4 clamped corner offsets (element units)
    float pw[64][9][4];            // 4 masked bilinear weights
    unsigned short A[64][72];      // cols tile [px][64 ck + 8 pad] bf16
    unsigned short Bt[16384];      // w tile  [256 o][64 kk] bf16 (swizzled)
  } s;
  float ytile[64][260];            // epilogue transpose buffer
};

__global__ __launch_bounds__(256, 2) void dcn_main(
    const float* __restrict__ xT, const float* __restrict__ offs,
    const float* __restrict__ boff, const unsigned short* __restrict__ wT4,
    float* __restrict__ y, float* __restrict__ stats) {
  __shared__ SmemArena u;
  const int bx = blockIdx.x;
  const int b = bx >> 6;
  const int pxbase = (bx & 63) << 6;
  const int t = threadIdx.x;
  const int lane = t & 63, wid = t >> 6;
  const float* xTb = xT + ((size_t)b << 12) * 256;

  // --- per-(pixel,k) sampling params into LDS ---
  for (int idx = t; idx < 576; idx += 256) {
    int p = idx / 9, k = idx - p * 9;
    int pxg = pxbase + p;
    int yy = pxg >> 6, xx = pxg & 63;
    const float* op = offs + ((size_t)b * 4096 + pxg) * 18 + k * 2;
    int kyi = k / 3, kxi = k - kyi * 3;
    float py = op[0] + boff[k * 2] + (float)(yy - 1 + kyi);
    float pxf = op[1] + boff[k * 2 + 1] + (float)(xx - 1 + kxi);
    float fy = floorf(py), fx = floorf(pxf);
    float dy = py - fy, dx = pxf - fx;
    int y0 = (int)fy, x0 = (int)fx;
    int y1 = y0 + 1, x1 = x0 + 1;
    float vy0 = ((unsigned)y0 < 64u) ? 1.f : 0.f;
    float vy1 = ((unsigned)y1 < 64u) ? 1.f : 0.f;
    float vx0 = ((unsigned)x0 < 64u) ? 1.f : 0.f;
    float vx1 = ((unsigned)x1 < 64u) ? 1.f : 0.f;
    int y0c = min(max(y0, 0), 63), y1c = min(max(y1, 0), 63);
    int x0c = min(max(x0, 0), 63), x1c = min(max(x1, 0), 63);
    u.s.poff[p][k][0] = ((y0c << 6) + x0c) << 8;
    u.s.poff[p][k][1] = ((y0c << 6) + x1c) << 8;
    u.s.poff[p][k][2] = ((y1c << 6) + x0c) << 8;
    u.s.poff[p][k][3] = ((y1c << 6) + x1c) << 8;
    u.s.pw[p][k][0] = (1.f - dy) * (1.f - dx) * vy0 * vx0;
    u.s.pw[p][k][1] = (1.f - dy) * dx * vy0 * vx1;
    u.s.pw[p][k][2] = dy * (1.f - dx) * vy1 * vx0;
    u.s.pw[p][k][3] = dy * dx * vy1 * vx1;
  }

  f32x4 acc[4][4];
#pragma unroll
  for (int i = 0; i < 4; ++i)
#pragma unroll
    for (int j = 0; j < 4; ++j) {
      f32x4 z = {0.f, 0.f, 0.f, 0.f};
      acc[i][j] = z;
    }

  __syncthreads();

  const int p_my = t >> 2;         // sampling: pixel owned by this thread
  const int cq = (t & 3) << 4;     // 16-channel sub-block

  for (int k = 0; k < 9; ++k) {
    int o00 = u.s.poff[p_my][k][0], o01 = u.s.poff[p_my][k][1];
    int o10 = u.s.poff[p_my][k][2], o11 = u.s.poff[p_my][k][3];
    float w00 = u.s.pw[p_my][k][0], w01 = u.s.pw[p_my][k][1];
    float w10 = u.s.pw[p_my][k][2], w11 = u.s.pw[p_my][k][3];
    for (int cc = 0; cc < 4; ++cc) {
      // --- stage B: 32KB pre-swizzled tile -> LDS (coalesced) ---
      {
        const u32x4* src = (const u32x4*)(wT4 + ((size_t)(k * 4 + cc) << 14));
        u32x4* dst = (u32x4*)u.s.Bt;
#pragma unroll
        for (int jj = 0; jj < 8; ++jj) dst[jj * 256 + t] = src[jj * 256 + t];
      }
      // --- stage A: bilinear-sample 16 channels of this pixel -> LDS bf16 ---
      {
        int cb = (cc << 6) + cq;
        const float* s00 = xTb + o00 + cb;
        const float* s01 = xTb + o01 + cb;
        const float* s10 = xTb + o10 + cb;
        const float* s11 = xTb + o11 + cb;
        u32 packed[8];
#pragma unroll
        for (int q = 0; q < 4; ++q) {
          f32x4 v = w00 * *(const f32x4*)(s00 + q * 4);
          v += w01 * *(const f32x4*)(s01 + q * 4);
          v += w10 * *(const f32x4*)(s10 + q * 4);
          v += w11 * *(const f32x4*)(s11 + q * 4);
          packed[q * 2] = pack2bf16(v.x, v.y);
          packed[q * 2 + 1] = pack2bf16(v.z, v.w);
        }
        u32x4* arow = (u32x4*)&u.s.A[p_my][cq];
        u32x4 t0 = {packed[0], packed[1], packed[2], packed[3]};
        u32x4 t1 = {packed[4], packed[5], packed[6], packed[7]};
        arow[0] = t0;
        arow[1] = t1;
      }
      __syncthreads();
      // --- MFMA: 64px x 64o per wave over this 64-ck chunk ---
      {
        const int obase = wid << 6;
#pragma unroll
        for (int s = 0; s < 2; ++s) {
          bf16x8 a[4], bb[4];
#pragma unroll
          for (int i = 0; i < 4; ++i) {
            int row = (i << 4) + (lane & 15);
            int kk = (s << 5) + ((lane >> 4) << 3);
            a[i] = *(const bf16x8*)&u.s.A[row][kk];
          }
#pragma unroll
          for (int j = 0; j < 4; ++j) {
            int o = obase + (j << 4) + (lane & 15);
            int kb = ((((s << 5) + ((lane >> 4) << 3)) << 1)) ^ ((o & 7) << 4);
            bb[j] = *(const bf16x8*)((const char*)u.s.Bt + o * 128 + kb);
          }
#pragma unroll
          for (int i = 0; i < 4; ++i)
#pragma unroll
            for (int j = 0; j < 4; ++j)
              acc[i][j] = __builtin_amdgcn_mfma_f32_16x16x32_bf16(a[i], bb[j], acc[i][j], 0, 0, 0);
        }
      }
      __syncthreads();
    }
  }

  // --- GroupNorm partial sums (D layout: col=lane&15 -> o, row=(lane>>4)*4+r -> px) ---
  const int obase = wid << 6;
#pragma unroll
  for (int j = 0; j < 4; ++j) {
    float s1 = 0.f, s2 = 0.f;
#pragma unroll
    for (int i = 0; i < 4; ++i)
#pragma unroll
      for (int r = 0; r < 4; ++r) {
        float v = acc[i][j][r];
        s1 += v;
        s2 += v * v;
      }
    s1 += __shfl_xor(s1, 1, 64);  s2 += __shfl_xor(s2, 1, 64);
    s1 += __shfl_xor(s1, 2, 64);  s2 += __shfl_xor(s2, 2, 64);
    s1 += __shfl_xor(s1, 4, 64);  s2 += __shfl_xor(s2, 4, 64);
    s1 += __shfl_xor(s1, 16, 64); s2 += __shfl_xor(s2, 16, 64);
    s1 += __shfl_xor(s1, 32, 64); s2 += __shfl_xor(s2, 32, 64);
    if ((lane & 0x37) == 0) {     // lanes 0 and 8: one per 8-channel group
      int g = (obase + (j << 4) + (lane & 15)) >> 3;
      atomicAdd(&stats[((b << 5) + g) * 2 + 0], s1);
      atomicAdd(&stats[((b << 5) + g) * 2 + 1], s2);
    }
  }

  // --- y write: acc -> LDS transpose -> coalesced y[b][px][o] ---
#pragma unroll
  for (int i = 0; i < 4; ++i)
#pragma unroll
    for (int j = 0; j < 4; ++j)
#pragma unroll
      for (int r = 0; r < 4; ++r) {
        int row = (i << 4) + ((lane >> 4) << 2) + r;
        int col = obase + (j << 4) + (lane & 15);
        u.ytile[row][col] = acc[i][j][r];
      }
  __syncthreads();
  {
    int row = t >> 2, oq = (t & 3) << 6;
    float* dst = y + ((size_t)b * 4096 + pxbase + row) * 256 + oq;
#pragma unroll
    for (int q = 0; q < 16; ++q)
      *(f32x4*)(dst + (q << 2)) = *(const f32x4*)&u.ytile[row][oq + (q << 2)];
  }
}

// ---------------------------------------------------------------------------
// K5: GroupNorm finalize + Mish + transpose to d_out[b][o][h][w]
// grid = 512 blocks of 256 (block = b, 64-pixel row group)
// ---------------------------------------------------------------------------
__global__ __launch_bounds__(256) void gn_mish(const float* __restrict__ y,
                                               const float* __restrict__ stats,
                                               const float* __restrict__ gamma,
                                               const float* __restrict__ beta,
                                               float* __restrict__ out) {
  __shared__ float tile[64][257];
  __shared__ float sm[32], sv[32], sg[256], sb[256];
  int bx = blockIdx.x;
  int b = bx >> 6;
  int pxbase = (bx & 63) << 6;
  int t = threadIdx.x;
  if (t < 32) {
    float s1 = stats[((b << 5) + t) * 2 + 0];
    float s2 = stats[((b << 5) + t) * 2 + 1];
    float mean = s1 * (1.f / 32768.f);
    float var = s2 * (1.f / 32768.f) - mean * mean;
    sm[t] = mean;
    sv[t] = rsqrtf(var + 1e-5f);
  }
  sg[t] = gamma[t];
  sb[t] = beta[t];
  __syncthreads();
  int row = t >> 2, oq = (t & 3) << 6;
  const float* src = y + ((size_t)b * 4096 + pxbase + row) * 256 + oq;
#pragma unroll
  for (int q = 0; q < 16; ++q) {
    f32x4 v = *(const f32x4*)(src + q * 4);
#pragma unroll
    for (int e = 0; e < 4; ++e) {
      int o = oq + q * 4 + e;
      float val = (v[e] - sm[o >> 3]) * sv[o >> 3] * sg[o] + sb[o];
      float ex = expf(fminf(val, 15.f));
      float num = ex * (ex + 2.f);
      float m = val * (num / (num + 2.f));
      if (val > 15.f) m = val;   // tanh(softplus) -> 1
      tile[row][o] = m;
    }
  }
  __syncthreads();
  int lane = t & 63, wid = t >> 6;
  size_t ob = ((size_t)b * 256) * 4096 + pxbase + lane;
#pragma unroll 4
  for (int i = 0; i < 64; ++i) {
    int o = (wid << 6) + i;
    out[ob + (size_t)o * 4096] = tile[lane][o];
  }
}

// ---------------------------------------------------------------------------
extern "C" void kernel_launch(void* const* d_in, const int* in_sizes, int n_in,
                              void* d_out, int out_size, void* d_ws, size_t ws_size,
                              hipStream_t stream) {
  const float* x     = (const float*)d_in[0];
  const float* w_off = (const float*)d_in[1];
  const float* b_off = (const float*)d_in[2];
  const float* w_dcn = (const float*)d_in[3];
  const float* gamma = (const float*)d_in[4];
  const float* beta  = (const float*)d_in[5];
  float* out = (float*)d_out;
  char* ws = (char*)d_ws;
  float* xT            = (float*)(ws);                       // 33,554,432 B
  float* y             = (float*)(ws + 33554432);            // 33,554,432 B
  float* offs          = (float*)(ws + 67108864);            //  2,359,296 B
  unsigned short* wT4  = (unsigned short*)(ws + 69468160);   //  1,179,648 B
  float* w2            = (float*)(ws + 70647808);            //    165,888 B
  float* stats         = (float*)(ws + 70813696);            //      2,048 B
  prep<<<dim3(4772), dim3(256), 0, stream>>>(w_dcn, w_off, wT4, w2, offs, stats);
  transpose_x<<<dim3(2048), dim3(256), 0, stream>>>(x, xT);
  conv_offset<<<dim3(512), dim3(256), 0, stream>>>(xT, w2, offs);
  dcn_main<<<dim3(512), dim3(256), 0, stream>>>(xT, offs, b_off, wT4, y, stats);
  gn_mish<<<dim3(512), dim3(256), 0, stream>>>(y, stats, gamma, beta, out);
}

// Round 2
// 242.527 us; speedup vs baseline: 1.8723x; 1.8723x over previous
//
#include <hip/hip_runtime.h>
#include <hip/hip_bf16.h>
#include <math.h>

typedef __bf16 bf16x8 __attribute__((ext_vector_type(8)));
typedef float f32x4 __attribute__((ext_vector_type(4)));
typedef unsigned int u32;
typedef u32 u32x4 __attribute__((ext_vector_type(4)));

// Problem constants: B=8, C=256, H=W=64, O=256, K=9, GN groups=32 (8 ch each)

__device__ inline u32 pack2bf16(float a, float b) {
  u32 ua = __float_as_uint(a);
  u32 ub = __float_as_uint(b);
  ua += 0x7fffu + ((ua >> 16) & 1u);   // RNE
  ub += 0x7fffu + ((ub >> 16) & 1u);
  return (ua >> 16) | (ub & 0xffff0000u);
}

// ---------------------------------------------------------------------------
// K0: prep — pack w_dcn into swizzled bf16 tiles, pack w_off into swizzled
// bf16 tiles (O padded 18->32), zero stats.
// wT4:   36 tiles (ck-chunks of 64), each [256 o][64 kk] bf16 = 32KB, byte
//        swizzle lin ^ ((o&7)<<4) -> conflict-free ds_read_b128 B-frags.
// wOffT: 36 tiles, each [32 o][64 kk] bf16 = 4KB, same swizzle.
// ---------------------------------------------------------------------------
__global__ void prep(const float* __restrict__ w_dcn, const float* __restrict__ w_off,
                     unsigned short* __restrict__ wT4, unsigned short* __restrict__ wOffT,
                     float* __restrict__ stats) {
  size_t id = (size_t)blockIdx.x * 256 + threadIdx.x;
  if (id < 589824) {               // 256 o * 2304 ck
    int o  = (int)(id / 2304);
    int ck = (int)(id % 2304);     // ck = k*256 + c
    int k = ck >> 8, c = ck & 255;
    float v = w_dcn[(size_t)(o * 256 + c) * 9 + k];
    u32 uv = __float_as_uint(v);
    uv += 0x7fffu + ((uv >> 16) & 1u);
    int tile = ck >> 6, kk = ck & 63;
    int lin = o * 128 + kk * 2;
    int swz = lin ^ ((o & 7) << 4);
    *(unsigned short*)((char*)wT4 + (size_t)tile * 32768 + swz) = (unsigned short)(uv >> 16);
  } else if (id < 663552) {        // 36 tiles * 32 o * 64 kk = 73728
    int r = (int)(id - 589824);
    int tile = r >> 11;            // k*4 + cc
    int rr = r & 2047;
    int o = rr >> 6, kk = rr & 63;
    int k = tile >> 2, cc = tile & 3;
    int c = (cc << 6) + kk;
    float v = (o < 18) ? w_off[(size_t)(o * 256 + c) * 9 + k] : 0.f;
    u32 uv = __float_as_uint(v);
    uv += 0x7fffu + ((uv >> 16) & 1u);
    int swz = (o * 128 + kk * 2) ^ ((o & 7) << 4);
    *(unsigned short*)((char*)wOffT + (size_t)tile * 4096 + swz) = (unsigned short)(uv >> 16);
  } else if (id < 664064) {        // zero stats: 512 floats
    stats[id - 663552] = 0.f;
  }
}

// ---------------------------------------------------------------------------
// K1: transpose x [B][C][H][W] -> xT [B][H][W][C]  (channels-last)
// grid: 8 b * 64 y * 4 cchunk = 2048 blocks of 256
// ---------------------------------------------------------------------------
__global__ __launch_bounds__(256) void transpose_x(const float* __restrict__ x,
                                                   float* __restrict__ xT) {
  __shared__ float tl[64][65];
  int bx = blockIdx.x;
  int b = bx >> 8;
  int y = (bx >> 2) & 63;
  int cb = (bx & 3) << 6;
  int t = threadIdx.x;
  int xi = t & 63, cr = t >> 6;
  size_t base = (((size_t)(b * 256 + cb) * 64 + y) << 6);
#pragma unroll
  for (int rep = 0; rep < 16; ++rep) {
    int cl = rep * 4 + cr;
    tl[cl][xi] = x[base + (size_t)cl * 4096 + xi];
  }
  __syncthreads();
  int xw = t >> 2, c4 = (t & 3) << 4;
  float* dst = xT + (((size_t)b * 4096) + y * 64 + xw) * 256 + cb + c4;
#pragma unroll
  for (int rep = 0; rep < 4; ++rep) {
    f32x4 v;
    v.x = tl[c4 + rep * 4 + 0][xw];
    v.y = tl[c4 + rep * 4 + 1][xw];
    v.z = tl[c4 + rep * 4 + 2][xw];
    v.w = tl[c4 + rep * 4 + 3][xw];
    *(f32x4*)(dst + rep * 4) = v;
  }
}

// ---------------------------------------------------------------------------
// K2: offset conv via MFMA.  offs[b][px][18] = conv(x, w_off) over all C.
// block = one 64-px image row x 32 padded O, 4 waves (wave w owns px rows
// [w*16, w*16+16)); grid = 8 b * 64 rows = 512 blocks of 256.
// A = integer-tap im2col tile [64 px][64 ck] bf16 (padded rows), B = wOffT.
// No atomics; each block computes the full C*K reduction for its row.
// ---------------------------------------------------------------------------
__global__ __launch_bounds__(256, 2) void conv_offset_mfma(
    const float* __restrict__ xT, const unsigned short* __restrict__ wOffT,
    float* __restrict__ offs) {
  __shared__ unsigned short A[64][72];     // +8 pad -> row stride 144B (9x16B)
  __shared__ unsigned short Bo[2048];      // [32 o][64 kk] bf16, swizzled
  const int bx = blockIdx.x;
  const int b = bx >> 6;
  const int y = bx & 63;
  const int t = threadIdx.x;
  const int lane = t & 63, wid = t >> 6;
  const float* xTb = xT + ((size_t)b << 12) * 256;
  const int p = t >> 2;            // pixel in row (= xx)
  const int q16 = (t & 3) << 4;    // 16-channel sub-block within 64-chunk

  f32x4 acc[2];
  {
    f32x4 z = {0.f, 0.f, 0.f, 0.f};
    acc[0] = z; acc[1] = z;
  }

  for (int k = 0; k < 9; ++k) {
    int ky = k / 3, kx = k - ky * 3;
    int ys = y - 1 + ky;
    int xs = p - 1 + kx;
    bool ok = ((unsigned)ys < 64u) && ((unsigned)xs < 64u);
    const float* sp = xTb + (size_t)(((ys << 6) + xs) << 8) + q16;
#pragma unroll
    for (int cc = 0; cc < 4; ++cc) {
      // stage B: 4KB w_off tile (coalesced, 16B/thread)
      {
        const u32x4* src = (const u32x4*)(wOffT + ((size_t)(k * 4 + cc) << 11));
        ((u32x4*)Bo)[t] = src[t];
      }
      // stage A: 16 channels of this pixel's tap -> bf16
      {
        u32 pk[8];
        if (ok) {
          const float* s0 = sp + (cc << 6);
#pragma unroll
          for (int q = 0; q < 4; ++q) {
            f32x4 v = *(const f32x4*)(s0 + q * 4);
            pk[q * 2]     = pack2bf16(v.x, v.y);
            pk[q * 2 + 1] = pack2bf16(v.z, v.w);
          }
        } else {
#pragma unroll
          for (int q = 0; q < 8; ++q) pk[q] = 0u;
        }
        u32x4* arow = (u32x4*)&A[p][q16];
        u32x4 t0 = {pk[0], pk[1], pk[2], pk[3]};
        u32x4 t1 = {pk[4], pk[5], pk[6], pk[7]};
        arow[0] = t0;
        arow[1] = t1;
      }
      __syncthreads();
      // MFMA: wave's 16 px x 32 o over this 64-ck chunk
#pragma unroll
      for (int s = 0; s < 2; ++s) {
        int kk = (s << 5) + ((lane >> 4) << 3);
        bf16x8 a = *(const bf16x8*)&A[(wid << 4) + (lane & 15)][kk];
#pragma unroll
        for (int j = 0; j < 2; ++j) {
          int o = (j << 4) + (lane & 15);
          int kb = (kk << 1) ^ ((o & 7) << 4);
          bf16x8 bv = *(const bf16x8*)((const char*)Bo + o * 128 + kb);
          acc[j] = __builtin_amdgcn_mfma_f32_16x16x32_bf16(a, bv, acc[j], 0, 0, 0);
        }
      }
      __syncthreads();
    }
  }

  // write offs (D layout: col=lane&15 -> o, row=(lane>>4)*4+r -> px-in-slice)
#pragma unroll
  for (int j = 0; j < 2; ++j) {
    int o = (j << 4) + (lane & 15);
    if (o < 18) {
#pragma unroll
      for (int r = 0; r < 4; ++r) {
        int pl = (wid << 4) + ((lane >> 4) << 2) + r;
        offs[((size_t)b * 4096 + (y << 6) + pl) * 18 + o] = acc[j][r];
      }
    }
  }
}

// ---------------------------------------------------------------------------
// K4: main fused kernel: bilinear sample -> bf16 MFMA GEMM -> GN partials + y
// block = 64 pixels x 256 O, 4 waves (wave w owns o in [w*64, w*64+64))
// grid = 8 b * 64 rowgroups = 512 blocks of 256
// ---------------------------------------------------------------------------
union SmemArena {
  struct {
    int poff[64][9][4];            // 4 clamped corner offsets (element units)
    float pw[64][9][4];            // 4 masked bilinear weights
    unsigned short A[64][72];      // cols tile [px][64 ck + 8 pad] bf16
    unsigned short Bt[16384];      // w tile  [256 o][64 kk] bf16 (swizzled)
  } s;
  float ytile[64][260];            // epilogue transpose buffer
};

__global__ __launch_bounds__(256, 2) void dcn_main(
    const float* __restrict__ xT, const float* __restrict__ offs,
    const float* __restrict__ boff, const unsigned short* __restrict__ wT4,
    float* __restrict__ y, float* __restrict__ stats) {
  __shared__ SmemArena u;
  const int bx = blockIdx.x;
  const int b = bx >> 6;
  const int pxbase = (bx & 63) << 6;
  const int t = threadIdx.x;
  const int lane = t & 63, wid = t >> 6;
  const float* xTb = xT + ((size_t)b << 12) * 256;

  // --- per-(pixel,k) sampling params into LDS ---
  for (int idx = t; idx < 576; idx += 256) {
    int p = idx / 9, k = idx - p * 9;
    int pxg = pxbase + p;
    int yy = pxg >> 6, xx = pxg & 63;
    const float* op = offs + ((size_t)b * 4096 + pxg) * 18 + k * 2;
    int kyi = k / 3, kxi = k - kyi * 3;
    float py = op[0] + boff[k * 2] + (float)(yy - 1 + kyi);
    float pxf = op[1] + boff[k * 2 + 1] + (float)(xx - 1 + kxi);
    float fy = floorf(py), fx = floorf(pxf);
    float dy = py - fy, dx = pxf - fx;
    int y0 = (int)fy, x0 = (int)fx;
    int y1 = y0 + 1, x1 = x0 + 1;
    float vy0 = ((unsigned)y0 < 64u) ? 1.f : 0.f;
    float vy1 = ((unsigned)y1 < 64u) ? 1.f : 0.f;
    float vx0 = ((unsigned)x0 < 64u) ? 1.f : 0.f;
    float vx1 = ((unsigned)x1 < 64u) ? 1.f : 0.f;
    int y0c = min(max(y0, 0), 63), y1c = min(max(y1, 0), 63);
    int x0c = min(max(x0, 0), 63), x1c = min(max(x1, 0), 63);
    u.s.poff[p][k][0] = ((y0c << 6) + x0c) << 8;
    u.s.poff[p][k][1] = ((y0c << 6) + x1c) << 8;
    u.s.poff[p][k][2] = ((y1c << 6) + x0c) << 8;
    u.s.poff[p][k][3] = ((y1c << 6) + x1c) << 8;
    u.s.pw[p][k][0] = (1.f - dy) * (1.f - dx) * vy0 * vx0;
    u.s.pw[p][k][1] = (1.f - dy) * dx * vy0 * vx1;
    u.s.pw[p][k][2] = dy * (1.f - dx) * vy1 * vx0;
    u.s.pw[p][k][3] = dy * dx * vy1 * vx1;
  }

  f32x4 acc[4][4];
#pragma unroll
  for (int i = 0; i < 4; ++i)
#pragma unroll
    for (int j = 0; j < 4; ++j) {
      f32x4 z = {0.f, 0.f, 0.f, 0.f};
      acc[i][j] = z;
    }

  __syncthreads();

  const int p_my = t >> 2;         // sampling: pixel owned by this thread
  const int cq = (t & 3) << 4;     // 16-channel sub-block

  for (int k = 0; k < 9; ++k) {
    int o00 = u.s.poff[p_my][k][0], o01 = u.s.poff[p_my][k][1];
    int o10 = u.s.poff[p_my][k][2], o11 = u.s.poff[p_my][k][3];
    float w00 = u.s.pw[p_my][k][0], w01 = u.s.pw[p_my][k][1];
    float w10 = u.s.pw[p_my][k][2], w11 = u.s.pw[p_my][k][3];
    for (int cc = 0; cc < 4; ++cc) {
      // --- stage B: 32KB pre-swizzled tile -> LDS (coalesced) ---
      {
        const u32x4* src = (const u32x4*)(wT4 + ((size_t)(k * 4 + cc) << 14));
        u32x4* dst = (u32x4*)u.s.Bt;
#pragma unroll
        for (int jj = 0; jj < 8; ++jj) dst[jj * 256 + t] = src[jj * 256 + t];
      }
      // --- stage A: bilinear-sample 16 channels of this pixel -> LDS bf16 ---
      {
        int cb = (cc << 6) + cq;
        const float* s00 = xTb + o00 + cb;
        const float* s01 = xTb + o01 + cb;
        const float* s10 = xTb + o10 + cb;
        const float* s11 = xTb + o11 + cb;
        u32 packed[8];
#pragma unroll
        for (int q = 0; q < 4; ++q) {
          f32x4 v = w00 * *(const f32x4*)(s00 + q * 4);
          v += w01 * *(const f32x4*)(s01 + q * 4);
          v += w10 * *(const f32x4*)(s10 + q * 4);
          v += w11 * *(const f32x4*)(s11 + q * 4);
          packed[q * 2] = pack2bf16(v.x, v.y);
          packed[q * 2 + 1] = pack2bf16(v.z, v.w);
        }
        u32x4* arow = (u32x4*)&u.s.A[p_my][cq];
        u32x4 t0 = {packed[0], packed[1], packed[2], packed[3]};
        u32x4 t1 = {packed[4], packed[5], packed[6], packed[7]};
        arow[0] = t0;
        arow[1] = t1;
      }
      __syncthreads();
      // --- MFMA: 64px x 64o per wave over this 64-ck chunk ---
      {
        const int obase = wid << 6;
#pragma unroll
        for (int s = 0; s < 2; ++s) {
          bf16x8 a[4], bb[4];
#pragma unroll
          for (int i = 0; i < 4; ++i) {
            int row = (i << 4) + (lane & 15);
            int kk = (s << 5) + ((lane >> 4) << 3);
            a[i] = *(const bf16x8*)&u.s.A[row][kk];
          }
#pragma unroll
          for (int j = 0; j < 4; ++j) {
            int o = obase + (j << 4) + (lane & 15);
            int kb = ((((s << 5) + ((lane >> 4) << 3)) << 1)) ^ ((o & 7) << 4);
            bb[j] = *(const bf16x8*)((const char*)u.s.Bt + o * 128 + kb);
          }
#pragma unroll
          for (int i = 0; i < 4; ++i)
#pragma unroll
            for (int j = 0; j < 4; ++j)
              acc[i][j] = __builtin_amdgcn_mfma_f32_16x16x32_bf16(a[i], bb[j], acc[i][j], 0, 0, 0);
        }
      }
      __syncthreads();
    }
  }

  // --- GroupNorm partial sums (D layout: col=lane&15 -> o, row=(lane>>4)*4+r -> px) ---
  const int obase = wid << 6;
#pragma unroll
  for (int j = 0; j < 4; ++j) {
    float s1 = 0.f, s2 = 0.f;
#pragma unroll
    for (int i = 0; i < 4; ++i)
#pragma unroll
      for (int r = 0; r < 4; ++r) {
        float v = acc[i][j][r];
        s1 += v;
        s2 += v * v;
      }
    s1 += __shfl_xor(s1, 1, 64);  s2 += __shfl_xor(s2, 1, 64);
    s1 += __shfl_xor(s1, 2, 64);  s2 += __shfl_xor(s2, 2, 64);
    s1 += __shfl_xor(s1, 4, 64);  s2 += __shfl_xor(s2, 4, 64);
    s1 += __shfl_xor(s1, 16, 64); s2 += __shfl_xor(s2, 16, 64);
    s1 += __shfl_xor(s1, 32, 64); s2 += __shfl_xor(s2, 32, 64);
    if ((lane & 0x37) == 0) {     // lanes 0 and 8: one per 8-channel group
      int g = (obase + (j << 4) + (lane & 15)) >> 3;
      atomicAdd(&stats[((b << 5) + g) * 2 + 0], s1);
      atomicAdd(&stats[((b << 5) + g) * 2 + 1], s2);
    }
  }

  // --- y write: acc -> LDS transpose -> coalesced y[b][px][o] ---
#pragma unroll
  for (int i = 0; i < 4; ++i)
#pragma unroll
    for (int j = 0; j < 4; ++j)
#pragma unroll
      for (int r = 0; r < 4; ++r) {
        int row = (i << 4) + ((lane >> 4) << 2) + r;
        int col = obase + (j << 4) + (lane & 15);
        u.ytile[row][col] = acc[i][j][r];
      }
  __syncthreads();
  {
    int row = t >> 2, oq = (t & 3) << 6;
    float* dst = y + ((size_t)b * 4096 + pxbase + row) * 256 + oq;
#pragma unroll
    for (int q = 0; q < 16; ++q)
      *(f32x4*)(dst + (q << 2)) = *(const f32x4*)&u.ytile[row][oq + (q << 2)];
  }
}

// ---------------------------------------------------------------------------
// K5: GroupNorm finalize + Mish + transpose to d_out[b][o][h][w]
// grid = 512 blocks of 256 (block = b, 64-pixel row group)
// ---------------------------------------------------------------------------
__global__ __launch_bounds__(256) void gn_mish(const float* __restrict__ y,
                                               const float* __restrict__ stats,
                                               const float* __restrict__ gamma,
                                               const float* __restrict__ beta,
                                               float* __restrict__ out) {
  __shared__ float tile[64][257];
  __shared__ float sm[32], sv[32], sg[256], sb[256];
  int bx = blockIdx.x;
  int b = bx >> 6;
  int pxbase = (bx & 63) << 6;
  int t = threadIdx.x;
  if (t < 32) {
    float s1 = stats[((b << 5) + t) * 2 + 0];
    float s2 = stats[((b << 5) + t) * 2 + 1];
    float mean = s1 * (1.f / 32768.f);
    float var = s2 * (1.f / 32768.f) - mean * mean;
    sm[t] = mean;
    sv[t] = rsqrtf(var + 1e-5f);
  }
  sg[t] = gamma[t];
  sb[t] = beta[t];
  __syncthreads();
  int row = t >> 2, oq = (t & 3) << 6;
  const float* src = y + ((size_t)b * 4096 + pxbase + row) * 256 + oq;
#pragma unroll
  for (int q = 0; q < 16; ++q) {
    f32x4 v = *(const f32x4*)(src + q * 4);
#pragma unroll
    for (int e = 0; e < 4; ++e) {
      int o = oq + q * 4 + e;
      float val = (v[e] - sm[o >> 3]) * sv[o >> 3] * sg[o] + sb[o];
      float ex = expf(fminf(val, 15.f));
      float num = ex * (ex + 2.f);
      float m = val * (num / (num + 2.f));
      if (val > 15.f) m = val;   // tanh(softplus) -> 1
      tile[row][o] = m;
    }
  }
  __syncthreads();
  int lane = t & 63, wid = t >> 6;
  size_t ob = ((size_t)b * 256) * 4096 + pxbase + lane;
#pragma unroll 4
  for (int i = 0; i < 64; ++i) {
    int o = (wid << 6) + i;
    out[ob + (size_t)o * 4096] = tile[lane][o];
  }
}

// ---------------------------------------------------------------------------
extern "C" void kernel_launch(void* const* d_in, const int* in_sizes, int n_in,
                              void* d_out, int out_size, void* d_ws, size_t ws_size,
                              hipStream_t stream) {
  const float* x     = (const float*)d_in[0];
  const float* w_off = (const float*)d_in[1];
  const float* b_off = (const float*)d_in[2];
  const float* w_dcn = (const float*)d_in[3];
  const float* gamma = (const float*)d_in[4];
  const float* beta  = (const float*)d_in[5];
  float* out = (float*)d_out;
  char* ws = (char*)d_ws;
  float* xT            = (float*)(ws);                       // 33,554,432 B
  float* y             = (float*)(ws + 33554432);            // 33,554,432 B
  float* offs          = (float*)(ws + 67108864);            //  2,359,296 B
  unsigned short* wT4  = (unsigned short*)(ws + 69468160);   //  1,179,648 B
  unsigned short* wOffT= (unsigned short*)(ws + 70647808);   //    147,456 B
  float* stats         = (float*)(ws + 70795264);            //      2,048 B
  prep<<<dim3(2594), dim3(256), 0, stream>>>(w_dcn, w_off, wT4, wOffT, stats);
  transpose_x<<<dim3(2048), dim3(256), 0, stream>>>(x, xT);
  conv_offset_mfma<<<dim3(512), dim3(256), 0, stream>>>(xT, wOffT, offs);
  dcn_main<<<dim3(512), dim3(256), 0, stream>>>(xT, offs, b_off, wT4, y, stats);
  gn_mish<<<dim3(512), dim3(256), 0, stream>>>(y, stats, gamma, beta, out);
}

// Round 3
// 149.472 us; speedup vs baseline: 3.0379x; 1.6226x over previous
//
#include <hip/hip_runtime.h>
#include <hip/hip_bf16.h>
#include <math.h>

typedef __bf16 bf16x8 __attribute__((ext_vector_type(8)));
typedef float f32x4 __attribute__((ext_vector_type(4)));
typedef unsigned int u32;
typedef u32 u32x4 __attribute__((ext_vector_type(4)));

// Problem constants: B=8, C=256, H=W=64, O=256, K=9, GN groups=32 (8 ch each)

__device__ inline u32 pack2bf16(float a, float b) {
  u32 ua = __float_as_uint(a);
  u32 ub = __float_as_uint(b);
  ua += 0x7fffu + ((ua >> 16) & 1u);   // RNE
  ub += 0x7fffu + ((ub >> 16) & 1u);
  return (ua >> 16) | (ub & 0xffff0000u);
}

// ---------------------------------------------------------------------------
// K0: prep — pack w_dcn into swizzled bf16 tiles, pack w_off into swizzled
// bf16 tiles (O padded 18->32), zero stats.
// wT4:   36 tiles (ck-chunks of 64), each [256 o][64 kk] bf16 = 32KB, byte
//        swizzle lin ^ ((o&7)<<4) -> conflict-free ds_read_b128 B-frags.
// wOffT: 36 tiles, each [32 o][64 kk] bf16 = 4KB, same swizzle.
// ---------------------------------------------------------------------------
__global__ void prep(const float* __restrict__ w_dcn, const float* __restrict__ w_off,
                     unsigned short* __restrict__ wT4, unsigned short* __restrict__ wOffT,
                     float* __restrict__ stats) {
  size_t id = (size_t)blockIdx.x * 256 + threadIdx.x;
  if (id < 589824) {               // 256 o * 2304 ck
    int o  = (int)(id / 2304);
    int ck = (int)(id % 2304);     // ck = k*256 + c
    int k = ck >> 8, c = ck & 255;
    float v = w_dcn[(size_t)(o * 256 + c) * 9 + k];
    u32 uv = __float_as_uint(v);
    uv += 0x7fffu + ((uv >> 16) & 1u);
    int tile = ck >> 6, kk = ck & 63;
    int lin = o * 128 + kk * 2;
    int swz = lin ^ ((o & 7) << 4);
    *(unsigned short*)((char*)wT4 + (size_t)tile * 32768 + swz) = (unsigned short)(uv >> 16);
  } else if (id < 663552) {        // 36 tiles * 32 o * 64 kk = 73728
    int r = (int)(id - 589824);
    int tile = r >> 11;            // k*4 + cc
    int rr = r & 2047;
    int o = rr >> 6, kk = rr & 63;
    int k = tile >> 2, cc = tile & 3;
    int c = (cc << 6) + kk;
    float v = (o < 18) ? w_off[(size_t)(o * 256 + c) * 9 + k] : 0.f;
    u32 uv = __float_as_uint(v);
    uv += 0x7fffu + ((uv >> 16) & 1u);
    int swz = (o * 128 + kk * 2) ^ ((o & 7) << 4);
    *(unsigned short*)((char*)wOffT + (size_t)tile * 4096 + swz) = (unsigned short)(uv >> 16);
  } else if (id < 664064) {        // zero stats: 512 floats
    stats[id - 663552] = 0.f;
  }
}

// ---------------------------------------------------------------------------
// K1: transpose x [B][C][H][W] -> xT [B][H][W][C] bf16  (channels-last)
// grid: 8 b * 64 y * 4 cchunk = 2048 blocks of 256
// ---------------------------------------------------------------------------
__global__ __launch_bounds__(256) void transpose_x(const float* __restrict__ x,
                                                   unsigned short* __restrict__ xT) {
  __shared__ float tl[64][65];
  int bx = blockIdx.x;
  int b = bx >> 8;
  int y = (bx >> 2) & 63;
  int cb = (bx & 3) << 6;
  int t = threadIdx.x;
  int xi = t & 63, cr = t >> 6;
  size_t base = (((size_t)(b * 256 + cb) * 64 + y) << 6);
#pragma unroll
  for (int rep = 0; rep < 16; ++rep) {
    int cl = rep * 4 + cr;
    tl[cl][xi] = x[base + (size_t)cl * 4096 + xi];
  }
  __syncthreads();
  int xw = t >> 2, c4 = (t & 3) << 4;
  unsigned short* dst = xT + (((size_t)b * 4096) + y * 64 + xw) * 256 + cb + c4;
  u32 pk[8];
#pragma unroll
  for (int e = 0; e < 8; ++e)
    pk[e] = pack2bf16(tl[c4 + 2 * e][xw], tl[c4 + 2 * e + 1][xw]);
  u32x4 v0 = {pk[0], pk[1], pk[2], pk[3]};
  u32x4 v1 = {pk[4], pk[5], pk[6], pk[7]};
  *(u32x4*)dst = v0;
  *((u32x4*)dst + 1) = v1;
}

// ---------------------------------------------------------------------------
// K2: offset conv via MFMA.  offs[b][px][18] = conv(x, w_off) over all C.
// block = one 64-px image row x 32 padded O, 4 waves; grid 512 (XCD-swizzled:
// XCD x owns image x -> its 2.1MB bf16 xT stays L2-resident).
// ---------------------------------------------------------------------------
__global__ __launch_bounds__(256, 2) void conv_offset_mfma(
    const unsigned short* __restrict__ xT, const unsigned short* __restrict__ wOffT,
    float* __restrict__ offs) {
  __shared__ unsigned short A[64][72];     // +8 pad -> row stride 144B (9x16B)
  __shared__ unsigned short Bo[2048];      // [32 o][64 kk] bf16, swizzled
  const int bx = blockIdx.x;
  const int lb = ((bx & 7) << 6) + (bx >> 3);   // XCD x -> image x
  const int b = lb >> 6;
  const int y = lb & 63;
  const int t = threadIdx.x;
  const int lane = t & 63, wid = t >> 6;
  const unsigned short* xTb = xT + ((size_t)b << 20);
  const int p = t >> 2;            // pixel in row (= xx)
  const int q16 = (t & 3) << 4;    // 16-channel sub-block within 64-chunk

  f32x4 acc[2];
  {
    f32x4 z = {0.f, 0.f, 0.f, 0.f};
    acc[0] = z; acc[1] = z;
  }

  for (int k = 0; k < 9; ++k) {
    int ky = k / 3, kx = k - ky * 3;
    int ys = y - 1 + ky;
    int xs = p - 1 + kx;
    bool ok = ((unsigned)ys < 64u) && ((unsigned)xs < 64u);
    const unsigned short* sp = xTb + (size_t)(((ys << 6) + xs) << 8) + q16;
#pragma unroll
    for (int cc = 0; cc < 4; ++cc) {
      // stage B: 4KB w_off tile (coalesced, 16B/thread)
      {
        const u32x4* src = (const u32x4*)(wOffT + ((size_t)(k * 4 + cc) << 11));
        ((u32x4*)Bo)[t] = src[t];
      }
      // stage A: 16 bf16 channels of this pixel's tap (already bf16)
      {
        u32x4 t0 = {0u, 0u, 0u, 0u}, t1 = {0u, 0u, 0u, 0u};
        if (ok) {
          const unsigned short* s0 = sp + (cc << 6);
          t0 = *(const u32x4*)s0;
          t1 = *(const u32x4*)(s0 + 8);
        }
        u32x4* arow = (u32x4*)&A[p][q16];
        arow[0] = t0;
        arow[1] = t1;
      }
      __syncthreads();
      // MFMA: wave's 16 px x 32 o over this 64-ck chunk
#pragma unroll
      for (int s = 0; s < 2; ++s) {
        int kk = (s << 5) + ((lane >> 4) << 3);
        bf16x8 a = *(const bf16x8*)&A[(wid << 4) + (lane & 15)][kk];
#pragma unroll
        for (int j = 0; j < 2; ++j) {
          int o = (j << 4) + (lane & 15);
          int kb = (kk << 1) ^ ((o & 7) << 4);
          bf16x8 bv = *(const bf16x8*)((const char*)Bo + o * 128 + kb);
          acc[j] = __builtin_amdgcn_mfma_f32_16x16x32_bf16(a, bv, acc[j], 0, 0, 0);
        }
      }
      __syncthreads();
    }
  }

  // write offs (D layout: col=lane&15 -> o, row=(lane>>4)*4+r -> px-in-slice)
#pragma unroll
  for (int j = 0; j < 2; ++j) {
    int o = (j << 4) + (lane & 15);
    if (o < 18) {
#pragma unroll
      for (int r = 0; r < 4; ++r) {
        int pl = (wid << 4) + ((lane >> 4) << 2) + r;
        offs[((size_t)b * 4096 + (y << 6) + pl) * 18 + o] = acc[j][r];
      }
    }
  }
}

// ---------------------------------------------------------------------------
// K4: main fused kernel: bilinear sample -> bf16 MFMA GEMM -> GN partials + y
// block = 128 pixels x 256 O, 8 waves (2 px-groups x 4 o-groups), 512 thr.
// grid = 256 (XCD-swizzled: XCD x owns image x). Double-buffered LDS; B via
// global_load_lds(16B); 2-phase: stage(t+1) || MFMA(t); setprio on MFMA.
// ---------------------------------------------------------------------------
__global__ __launch_bounds__(512, 2) void dcn_main(
    const unsigned short* __restrict__ xT, const float* __restrict__ offs,
    const float* __restrict__ boff, const unsigned short* __restrict__ wT4,
    float* __restrict__ y, float* __restrict__ stats) {
  __shared__ unsigned short A[2][128][72];   // 36,864 B (row stride 144B)
  __shared__ unsigned short Bt[2][16384];    // 65,536 B ([256 o][64 kk] swz)
  __shared__ unsigned short poffu[128][9][4];//  9,216 B (y*64+x per corner)
  __shared__ float pw[128][9][4];            // 18,432 B

  const int bx = blockIdx.x;
  const int lb = ((bx & 7) << 5) + (bx >> 3);   // XCD x -> image x
  const int b = lb >> 5;
  const int pxbase = (lb & 31) << 7;            // 128-px group (2 rows)
  const int t = threadIdx.x;
  const int lane = t & 63, wid = t >> 6;
  const int wr = wid >> 2, wc = wid & 3;        // wave grid 2 x 4
  const unsigned short* xTb = xT + ((size_t)b << 20);

  // --- per-(pixel,k) sampling params into LDS ---
  for (int idx = t; idx < 1152; idx += 512) {
    int p = idx / 9, k = idx - p * 9;
    int pxg = pxbase + p;
    int yy = pxg >> 6, xx = pxg & 63;
    const float* op = offs + ((size_t)b * 4096 + pxg) * 18 + k * 2;
    int kyi = k / 3, kxi = k - kyi * 3;
    float py = op[0] + boff[k * 2] + (float)(yy - 1 + kyi);
    float pxf = op[1] + boff[k * 2 + 1] + (float)(xx - 1 + kxi);
    float fy = floorf(py), fx = floorf(pxf);
    float dy = py - fy, dx = pxf - fx;
    int y0 = (int)fy, x0 = (int)fx;
    int y1 = y0 + 1, x1 = x0 + 1;
    float vy0 = ((unsigned)y0 < 64u) ? 1.f : 0.f;
    float vy1 = ((unsigned)y1 < 64u) ? 1.f : 0.f;
    float vx0 = ((unsigned)x0 < 64u) ? 1.f : 0.f;
    float vx1 = ((unsigned)x1 < 64u) ? 1.f : 0.f;
    int y0c = min(max(y0, 0), 63), y1c = min(max(y1, 0), 63);
    int x0c = min(max(x0, 0), 63), x1c = min(max(x1, 0), 63);
    poffu[p][k][0] = (unsigned short)((y0c << 6) + x0c);
    poffu[p][k][1] = (unsigned short)((y0c << 6) + x1c);
    poffu[p][k][2] = (unsigned short)((y1c << 6) + x0c);
    poffu[p][k][3] = (unsigned short)((y1c << 6) + x1c);
    pw[p][k][0] = (1.f - dy) * (1.f - dx) * vy0 * vx0;
    pw[p][k][1] = (1.f - dy) * dx * vy0 * vx1;
    pw[p][k][2] = dy * (1.f - dx) * vy1 * vx0;
    pw[p][k][3] = dy * dx * vy1 * vx1;
  }

  f32x4 acc[4][4];
#pragma unroll
  for (int i = 0; i < 4; ++i)
#pragma unroll
    for (int j = 0; j < 4; ++j) {
      f32x4 z = {0.f, 0.f, 0.f, 0.f};
      acc[i][j] = z;
    }

  const int p_my = t >> 2;         // sampling: pixel owned by this thread
  const int cq = (t & 3) << 4;     // 16-channel sub-block

  __syncthreads();                 // params ready

  auto stage = [&](int tt, int d) {
    // --- B: async global->LDS, 64B/thread, linear dest (pre-swizzled src) ---
    {
      const char* src = (const char*)wT4 + ((size_t)tt << 15);
      char* dstb = (char*)&Bt[d][0] + (wid << 12);
#pragma unroll
      for (int i2 = 0; i2 < 4; ++i2) {
        __builtin_amdgcn_global_load_lds(
            (const __attribute__((address_space(1))) u32*)(src + (wid << 12) + (i2 << 10) + (lane << 4)),
            (__attribute__((address_space(3))) u32*)(dstb + (i2 << 10)),
            16, 0, 0);
      }
    }
    // --- A: bilinear-sample 16 bf16 channels of this thread's pixel ---
    {
      int k = tt >> 2, cc = tt & 3;
      int cb = (cc << 6) + cq;
      const unsigned short* s00 = xTb + ((int)poffu[p_my][k][0] << 8) + cb;
      const unsigned short* s01 = xTb + ((int)poffu[p_my][k][1] << 8) + cb;
      const unsigned short* s10 = xTb + ((int)poffu[p_my][k][2] << 8) + cb;
      const unsigned short* s11 = xTb + ((int)poffu[p_my][k][3] << 8) + cb;
      float w00 = pw[p_my][k][0], w01 = pw[p_my][k][1];
      float w10 = pw[p_my][k][2], w11 = pw[p_my][k][3];
      u32x4 a00 = *(const u32x4*)s00, b00 = *(const u32x4*)(s00 + 8);
      u32x4 a01 = *(const u32x4*)s01, b01 = *(const u32x4*)(s01 + 8);
      u32x4 a10 = *(const u32x4*)s10, b10 = *(const u32x4*)(s10 + 8);
      u32x4 a11 = *(const u32x4*)s11, b11 = *(const u32x4*)(s11 + 8);
      u32 outp[8];
#pragma unroll
      for (int e = 0; e < 8; ++e) {
        u32 u00 = (e < 4) ? a00[e] : b00[e - 4];
        u32 u01 = (e < 4) ? a01[e] : b01[e - 4];
        u32 u10 = (e < 4) ? a10[e] : b10[e - 4];
        u32 u11 = (e < 4) ? a11[e] : b11[e - 4];
        float lo = w00 * __uint_as_float(u00 << 16)
                 + w01 * __uint_as_float(u01 << 16)
                 + w10 * __uint_as_float(u10 << 16)
                 + w11 * __uint_as_float(u11 << 16);
        float hi = w00 * __uint_as_float(u00 & 0xffff0000u)
                 + w01 * __uint_as_float(u01 & 0xffff0000u)
                 + w10 * __uint_as_float(u10 & 0xffff0000u)
                 + w11 * __uint_as_float(u11 & 0xffff0000u);
        outp[e] = pack2bf16(lo, hi);
      }
      u32x4* arow = (u32x4*)&A[d][p_my][cq];
      u32x4 t0 = {outp[0], outp[1], outp[2], outp[3]};
      u32x4 t1 = {outp[4], outp[5], outp[6], outp[7]};
      arow[0] = t0;
      arow[1] = t1;
    }
  };

  stage(0, 0);
  __syncthreads();

  const int rbase = wr << 6;
  const int obase = wc << 6;
  int cur = 0;
  for (int tt = 0; tt < 36; ++tt) {
    if (tt < 35) stage(tt + 1, cur ^ 1);
    __builtin_amdgcn_s_setprio(1);
#pragma unroll
    for (int s = 0; s < 2; ++s) {
      bf16x8 a[4], bb[4];
#pragma unroll
      for (int i = 0; i < 4; ++i) {
        int row = rbase + (i << 4) + (lane & 15);
        int kk = (s << 5) + ((lane >> 4) << 3);
        a[i] = *(const bf16x8*)&A[cur][row][kk];
      }
#pragma unroll
      for (int j = 0; j < 4; ++j) {
        int o = obase + (j << 4) + (lane & 15);
        int kb = ((((s << 5) + ((lane >> 4) << 3)) << 1)) ^ ((o & 7) << 4);
        bb[j] = *(const bf16x8*)((const char*)&Bt[cur][0] + o * 128 + kb);
      }
#pragma unroll
      for (int i = 0; i < 4; ++i)
#pragma unroll
        for (int j = 0; j < 4; ++j)
          acc[i][j] = __builtin_amdgcn_mfma_f32_16x16x32_bf16(a[i], bb[j], acc[i][j], 0, 0, 0);
    }
    __builtin_amdgcn_s_setprio(0);
    __syncthreads();
    cur ^= 1;
  }

  // --- GroupNorm partial sums (D layout: col=lane&15 -> o, row=(lane>>4)*4+r -> px) ---
#pragma unroll
  for (int j = 0; j < 4; ++j) {
    float s1 = 0.f, s2 = 0.f;
#pragma unroll
    for (int i = 0; i < 4; ++i)
#pragma unroll
      for (int r = 0; r < 4; ++r) {
        float v = acc[i][j][r];
        s1 += v;
        s2 += v * v;
      }
    s1 += __shfl_xor(s1, 1, 64);  s2 += __shfl_xor(s2, 1, 64);
    s1 += __shfl_xor(s1, 2, 64);  s2 += __shfl_xor(s2, 2, 64);
    s1 += __shfl_xor(s1, 4, 64);  s2 += __shfl_xor(s2, 4, 64);
    s1 += __shfl_xor(s1, 16, 64); s2 += __shfl_xor(s2, 16, 64);
    s1 += __shfl_xor(s1, 32, 64); s2 += __shfl_xor(s2, 32, 64);
    if ((lane & 0x37) == 0) {     // lanes 0 and 8: one per 8-channel group
      int g = (obase + (j << 4) + (lane & 15)) >> 3;
      atomicAdd(&stats[((b << 5) + g) * 2 + 0], s1);
      atomicAdd(&stats[((b << 5) + g) * 2 + 1], s2);
    }
  }

  // --- y write: direct stores (16 lanes x 4B = one 64B segment each) ---
  {
    size_t pxb = (size_t)b * 4096 + pxbase + rbase + ((lane >> 4) << 2);
    int o = obase + (lane & 15);
#pragma unroll
    for (int i = 0; i < 4; ++i)
#pragma unroll
      for (int r = 0; r < 4; ++r) {
        float* dst = y + (pxb + (i << 4) + r) * 256 + o;
#pragma unroll
        for (int j = 0; j < 4; ++j)
          dst[j << 4] = acc[i][j][r];
      }
  }
}

// ---------------------------------------------------------------------------
// K5: GroupNorm finalize + Mish + transpose to d_out[b][o][h][w]
// grid = 512 blocks of 256 (block = b, 64-pixel row group)
// ---------------------------------------------------------------------------
__global__ __launch_bounds__(256) void gn_mish(const float* __restrict__ y,
                                               const float* __restrict__ stats,
                                               const float* __restrict__ gamma,
                                               const float* __restrict__ beta,
                                               float* __restrict__ out) {
  __shared__ float tile[64][257];
  __shared__ float sm[32], sv[32], sg[256], sb[256];
  int bx = blockIdx.x;
  int b = bx >> 6;
  int pxbase = (bx & 63) << 6;
  int t = threadIdx.x;
  if (t < 32) {
    float s1 = stats[((b << 5) + t) * 2 + 0];
    float s2 = stats[((b << 5) + t) * 2 + 1];
    float mean = s1 * (1.f / 32768.f);
    float var = s2 * (1.f / 32768.f) - mean * mean;
    sm[t] = mean;
    sv[t] = rsqrtf(var + 1e-5f);
  }
  sg[t] = gamma[t];
  sb[t] = beta[t];
  __syncthreads();
  int row = t >> 2, oq = (t & 3) << 6;
  const float* src = y + ((size_t)b * 4096 + pxbase + row) * 256 + oq;
#pragma unroll
  for (int q = 0; q < 16; ++q) {
    f32x4 v = *(const f32x4*)(src + q * 4);
#pragma unroll
    for (int e = 0; e < 4; ++e) {
      int o = oq + q * 4 + e;
      float val = (v[e] - sm[o >> 3]) * sv[o >> 3] * sg[o] + sb[o];
      float ex = expf(fminf(val, 15.f));
      float num = ex * (ex + 2.f);
      float m = val * (num / (num + 2.f));
      if (val > 15.f) m = val;   // tanh(softplus) -> 1
      tile[row][o] = m;
    }
  }
  __syncthreads();
  int lane = t & 63, wid = t >> 6;
  size_t ob = ((size_t)b * 256) * 4096 + pxbase + lane;
#pragma unroll 4
  for (int i = 0; i < 64; ++i) {
    int o = (wid << 6) + i;
    out[ob + (size_t)o * 4096] = tile[lane][o];
  }
}

// ---------------------------------------------------------------------------
extern "C" void kernel_launch(void* const* d_in, const int* in_sizes, int n_in,
                              void* d_out, int out_size, void* d_ws, size_t ws_size,
                              hipStream_t stream) {
  const float* x     = (const float*)d_in[0];
  const float* w_off = (const float*)d_in[1];
  const float* b_off = (const float*)d_in[2];
  const float* w_dcn = (const float*)d_in[3];
  const float* gamma = (const float*)d_in[4];
  const float* beta  = (const float*)d_in[5];
  float* out = (float*)d_out;
  char* ws = (char*)d_ws;
  unsigned short* xT   = (unsigned short*)(ws);              // 16,777,216 B (bf16)
  float* y             = (float*)(ws + 16777216);            // 33,554,432 B
  float* offs          = (float*)(ws + 50331648);            //  2,359,296 B
  unsigned short* wT4  = (unsigned short*)(ws + 52690944);   //  1,179,648 B
  unsigned short* wOffT= (unsigned short*)(ws + 53870592);   //    147,456 B
  float* stats         = (float*)(ws + 54018048);            //      2,048 B
  prep<<<dim3(2594), dim3(256), 0, stream>>>(w_dcn, w_off, wT4, wOffT, stats);
  transpose_x<<<dim3(2048), dim3(256), 0, stream>>>(x, xT);
  conv_offset_mfma<<<dim3(512), dim3(256), 0, stream>>>(xT, wOffT, offs);
  dcn_main<<<dim3(256), dim3(512), 0, stream>>>(xT, offs, b_off, wT4, y, stats);
  gn_mish<<<dim3(512), dim3(256), 0, stream>>>(y, stats, gamma, beta, out);
}

// Round 4
// 138.686 us; speedup vs baseline: 3.2741x; 1.0778x over previous
//
#include <hip/hip_runtime.h>
#include <hip/hip_bf16.h>
#include <math.h>

typedef __bf16 bf16x8 __attribute__((ext_vector_type(8)));
typedef float f32x4 __attribute__((ext_vector_type(4)));
typedef unsigned int u32;
typedef u32 u32x4 __attribute__((ext_vector_type(4)));
typedef u32 u32x2 __attribute__((ext_vector_type(2)));

// Problem constants: B=8, C=256, H=W=64, O=256, K=9, GN groups=32 (8 ch each)

__device__ inline u32 pack2bf16(float a, float b) {
  u32 ua = __float_as_uint(a);
  u32 ub = __float_as_uint(b);
  ua += 0x7fffu + ((ua >> 16) & 1u);   // RNE
  ub += 0x7fffu + ((ub >> 16) & 1u);
  return (ua >> 16) | (ub & 0xffff0000u);
}

// ---------------------------------------------------------------------------
// K0: prep — pack w_dcn into swizzled bf16 tiles, pack w_off into swizzled
// bf16 tiles (O padded 18->32), zero stats.
// wT4:   36 tiles (ck-chunks of 64), each [256 o][64 kk] bf16 = 32KB, byte
//        swizzle lin ^ ((o&7)<<4) -> conflict-free ds_read_b128 B-frags.
// wOffT: 36 tiles, each [32 o][64 kk] bf16 = 4KB, same swizzle.
// ---------------------------------------------------------------------------
__global__ void prep(const float* __restrict__ w_dcn, const float* __restrict__ w_off,
                     unsigned short* __restrict__ wT4, unsigned short* __restrict__ wOffT,
                     float* __restrict__ stats) {
  size_t id = (size_t)blockIdx.x * 256 + threadIdx.x;
  if (id < 589824) {               // 256 o * 2304 ck
    int o  = (int)(id / 2304);
    int ck = (int)(id % 2304);     // ck = k*256 + c
    int k = ck >> 8, c = ck & 255;
    float v = w_dcn[(size_t)(o * 256 + c) * 9 + k];
    u32 uv = __float_as_uint(v);
    uv += 0x7fffu + ((uv >> 16) & 1u);
    int tile = ck >> 6, kk = ck & 63;
    int lin = o * 128 + kk * 2;
    int swz = lin ^ ((o & 7) << 4);
    *(unsigned short*)((char*)wT4 + (size_t)tile * 32768 + swz) = (unsigned short)(uv >> 16);
  } else if (id < 663552) {        // 36 tiles * 32 o * 64 kk = 73728
    int r = (int)(id - 589824);
    int tile = r >> 11;            // k*4 + cc
    int rr = r & 2047;
    int o = rr >> 6, kk = rr & 63;
    int k = tile >> 2, cc = tile & 3;
    int c = (cc << 6) + kk;
    float v = (o < 18) ? w_off[(size_t)(o * 256 + c) * 9 + k] : 0.f;
    u32 uv = __float_as_uint(v);
    uv += 0x7fffu + ((uv >> 16) & 1u);
    int swz = (o * 128 + kk * 2) ^ ((o & 7) << 4);
    *(unsigned short*)((char*)wOffT + (size_t)tile * 4096 + swz) = (unsigned short)(uv >> 16);
  } else if (id < 664064) {        // zero stats: 512 floats
    stats[id - 663552] = 0.f;
  }
}

// ---------------------------------------------------------------------------
// K1: transpose x [B][C][H][W] -> xT [B][H][W][C] bf16  (channels-last)
// grid: 8 b * 64 y * 4 cchunk = 2048 blocks of 256
// ---------------------------------------------------------------------------
__global__ __launch_bounds__(256) void transpose_x(const float* __restrict__ x,
                                                   unsigned short* __restrict__ xT) {
  __shared__ float tl[64][65];
  int bx = blockIdx.x;
  int b = bx >> 8;
  int y = (bx >> 2) & 63;
  int cb = (bx & 3) << 6;
  int t = threadIdx.x;
  int xi = t & 63, cr = t >> 6;
  size_t base = (((size_t)(b * 256 + cb) * 64 + y) << 6);
#pragma unroll
  for (int rep = 0; rep < 16; ++rep) {
    int cl = rep * 4 + cr;
    tl[cl][xi] = x[base + (size_t)cl * 4096 + xi];
  }
  __syncthreads();
  int xw = t >> 2, c4 = (t & 3) << 4;
  unsigned short* dst = xT + (((size_t)b * 4096) + y * 64 + xw) * 256 + cb + c4;
  u32 pk[8];
#pragma unroll
  for (int e = 0; e < 8; ++e)
    pk[e] = pack2bf16(tl[c4 + 2 * e][xw], tl[c4 + 2 * e + 1][xw]);
  u32x4 v0 = {pk[0], pk[1], pk[2], pk[3]};
  u32x4 v1 = {pk[4], pk[5], pk[6], pk[7]};
  *(u32x4*)dst = v0;
  *((u32x4*)dst + 1) = v1;
}

// ---------------------------------------------------------------------------
// K2: offset conv via MFMA, pipelined (T14): issue loads(t+1) -> MFMA(t) ->
// write(t+1). A: [2][64][64] bf16 XOR-swizzled; B via global_load_lds.
// grid 512 (XCD-swizzled: XCD x owns image x).
// ---------------------------------------------------------------------------
__global__ __launch_bounds__(256, 2) void conv_offset_mfma(
    const unsigned short* __restrict__ xT, const unsigned short* __restrict__ wOffT,
    float* __restrict__ offs) {
  __shared__ unsigned short A[2][64][64];  // 16KB, byte ^= (row&7)<<4
  __shared__ unsigned short Bo[2][2048];   // 8KB  ([32 o][64 kk], swizzled)
  const int bx = blockIdx.x;
  const int lb = ((bx & 7) << 6) + (bx >> 3);   // XCD x -> image x
  const int b = lb >> 6;
  const int y = lb & 63;
  const int t = threadIdx.x;
  const int lane = t & 63, wid = t >> 6;
  const unsigned short* xTb = xT + ((size_t)b << 20);
  const int p = t >> 2;            // pixel in row (= xx)
  const int q16 = (t & 3) << 4;    // 16-channel sub-block within 64-chunk

  f32x4 acc[2];
  {
    f32x4 z = {0.f, 0.f, 0.f, 0.f};
    acc[0] = z; acc[1] = z;
  }

  u32x4 ra = {0u,0u,0u,0u}, rb = {0u,0u,0u,0u};

  auto issue = [&](int tt, int d) {
    int k = tt >> 2, cc = tt & 3;
    int ky = k / 3, kx = k - ky * 3;
    int ys = y - 1 + ky;
    int xs = p - 1 + kx;
    bool ok = ((unsigned)ys < 64u) && ((unsigned)xs < 64u);
    u32x4 z = {0u,0u,0u,0u};
    ra = z; rb = z;
    if (ok) {
      const unsigned short* s0 = xTb + (size_t)(((ys << 6) + xs) << 8) + (cc << 6) + q16;
      ra = *(const u32x4*)s0;
      rb = *(const u32x4*)(s0 + 8);
    }
    // B: async global->LDS (linear dest, pre-swizzled source)
    __builtin_amdgcn_global_load_lds(
        (const __attribute__((address_space(1))) u32*)((const char*)wOffT + ((size_t)tt << 12) + (wid << 10) + (lane << 4)),
        (__attribute__((address_space(3))) u32*)((char*)&Bo[d][0] + (wid << 10)),
        16, 0, 0);
  };
  auto writeA = [&](int d) {
    char* dst = (char*)&A[d][0][0] + p * 128;
    int b0 = (t & 3) << 5;
    int sw = (p & 7) << 4;
    *(u32x4*)(dst + (b0 ^ sw)) = ra;
    *(u32x4*)(dst + ((b0 + 16) ^ sw)) = rb;
  };

  issue(0, 0);
  writeA(0);
  __syncthreads();

  int cur = 0;
  for (int tt = 0; tt < 36; ++tt) {
    if (tt < 35) issue(tt + 1, cur ^ 1);
#pragma unroll
    for (int s = 0; s < 2; ++s) {
      int row = (wid << 4) + (lane & 15);
      int bir = ((s << 6) + ((lane >> 4) << 4)) ^ ((row & 7) << 4);
      bf16x8 a = *(const bf16x8*)((const char*)&A[cur][0][0] + row * 128 + bir);
#pragma unroll
      for (int j = 0; j < 2; ++j) {
        int o = (j << 4) + (lane & 15);
        int kb = ((s << 6) + ((lane >> 4) << 4)) ^ ((o & 7) << 4);
        bf16x8 bv = *(const bf16x8*)((const char*)&Bo[cur][0] + o * 128 + kb);
        acc[j] = __builtin_amdgcn_mfma_f32_16x16x32_bf16(a, bv, acc[j], 0, 0, 0);
      }
    }
    if (tt < 35) writeA(cur ^ 1);
    __syncthreads();
    cur ^= 1;
  }

  // write offs (D layout: col=lane&15 -> o, row=(lane>>4)*4+r -> px-in-slice)
#pragma unroll
  for (int j = 0; j < 2; ++j) {
    int o = (j << 4) + (lane & 15);
    if (o < 18) {
#pragma unroll
      for (int r = 0; r < 4; ++r) {
        int pl = (wid << 4) + ((lane >> 4) << 2) + r;
        offs[((size_t)b * 4096 + (y << 6) + pl) * 18 + o] = acc[j][r];
      }
    }
  }
}

// ---------------------------------------------------------------------------
// K4: main fused kernel: bilinear sample -> bf16 MFMA GEMM -> GN partials + y
// block = 128 pixels x 256 O, 8 waves (2 px x 4 o), 512 thr, grid 256
// (XCD-swizzled). T14 pipeline: issue A-loads(t+1)+B-gload_lds(t+1) ->
// MFMA(t) -> pack/ds_write(t+1) -> barrier. A XOR-swizzled [2][128][64].
// Epilogue: acc -> ytile[o][px] bf16 -> y[b][o][px] bf16.
// ---------------------------------------------------------------------------
union Arena {
  struct {
    unsigned short A[2][128][64];   // 32,768 B (byte ^= (row&7)<<4)
    unsigned short Bt[2][16384];    // 65,536 B ([256 o][64 kk] swz)
  } m;
  unsigned short ytile[256][136];   // 69,632 B (o-major epilogue buffer)
};

__global__ __launch_bounds__(512, 2) void dcn_main(
    const unsigned short* __restrict__ xT, const float* __restrict__ offs,
    const float* __restrict__ boff, const unsigned short* __restrict__ wT4,
    unsigned short* __restrict__ yb, float* __restrict__ stats) {
  __shared__ Arena ar;
  __shared__ unsigned short poffu[128][9][4];  //  9,216 B
  __shared__ float pw[128][9][4];              // 18,432 B

  const int bx = blockIdx.x;
  const int lb = ((bx & 7) << 5) + (bx >> 3);   // XCD x -> image x
  const int b = lb >> 5;
  const int pxbase = (lb & 31) << 7;            // 128-px group (2 rows)
  const int t = threadIdx.x;
  const int lane = t & 63, wid = t >> 6;
  const int wr = wid >> 2, wc = wid & 3;        // wave grid 2 x 4
  const unsigned short* xTb = xT + ((size_t)b << 20);

  // --- per-(pixel,k) sampling params into LDS ---
  for (int idx = t; idx < 1152; idx += 512) {
    int p = idx / 9, k = idx - p * 9;
    int pxg = pxbase + p;
    int yy = pxg >> 6, xx = pxg & 63;
    const float* op = offs + ((size_t)b * 4096 + pxg) * 18 + k * 2;
    int kyi = k / 3, kxi = k - kyi * 3;
    float py = op[0] + boff[k * 2] + (float)(yy - 1 + kyi);
    float pxf = op[1] + boff[k * 2 + 1] + (float)(xx - 1 + kxi);
    float fy = floorf(py), fx = floorf(pxf);
    float dy = py - fy, dx = pxf - fx;
    int y0 = (int)fy, x0 = (int)fx;
    int y1 = y0 + 1, x1 = x0 + 1;
    float vy0 = ((unsigned)y0 < 64u) ? 1.f : 0.f;
    float vy1 = ((unsigned)y1 < 64u) ? 1.f : 0.f;
    float vx0 = ((unsigned)x0 < 64u) ? 1.f : 0.f;
    float vx1 = ((unsigned)x1 < 64u) ? 1.f : 0.f;
    int y0c = min(max(y0, 0), 63), y1c = min(max(y1, 0), 63);
    int x0c = min(max(x0, 0), 63), x1c = min(max(x1, 0), 63);
    poffu[p][k][0] = (unsigned short)((y0c << 6) + x0c);
    poffu[p][k][1] = (unsigned short)((y0c << 6) + x1c);
    poffu[p][k][2] = (unsigned short)((y1c << 6) + x0c);
    poffu[p][k][3] = (unsigned short)((y1c << 6) + x1c);
    pw[p][k][0] = (1.f - dy) * (1.f - dx) * vy0 * vx0;
    pw[p][k][1] = (1.f - dy) * dx * vy0 * vx1;
    pw[p][k][2] = dy * (1.f - dx) * vy1 * vx0;
    pw[p][k][3] = dy * dx * vy1 * vx1;
  }

  f32x4 acc[4][4];
#pragma unroll
  for (int i = 0; i < 4; ++i)
#pragma unroll
    for (int j = 0; j < 4; ++j) {
      f32x4 z = {0.f, 0.f, 0.f, 0.f};
      acc[i][j] = z;
    }

  const int p_my = t >> 2;         // sampling: pixel owned by this thread
  const int cq = (t & 3) << 4;     // 16-channel sub-block

  __syncthreads();                 // params ready

  // in-flight sample registers (4 corners x 2 vecs)
  u32x4 r00a, r00b, r01a, r01b, r10a, r10b, r11a, r11b;
  float w00, w01, w10, w11;

  auto issueA = [&](int tt) {
    int k = tt >> 2, cc = tt & 3;
    int cb = (cc << 6) + cq;
    const unsigned short* s00 = xTb + ((int)poffu[p_my][k][0] << 8) + cb;
    const unsigned short* s01 = xTb + ((int)poffu[p_my][k][1] << 8) + cb;
    const unsigned short* s10 = xTb + ((int)poffu[p_my][k][2] << 8) + cb;
    const unsigned short* s11 = xTb + ((int)poffu[p_my][k][3] << 8) + cb;
    w00 = pw[p_my][k][0]; w01 = pw[p_my][k][1];
    w10 = pw[p_my][k][2]; w11 = pw[p_my][k][3];
    r00a = *(const u32x4*)s00; r00b = *(const u32x4*)(s00 + 8);
    r01a = *(const u32x4*)s01; r01b = *(const u32x4*)(s01 + 8);
    r10a = *(const u32x4*)s10; r10b = *(const u32x4*)(s10 + 8);
    r11a = *(const u32x4*)s11; r11b = *(const u32x4*)(s11 + 8);
  };
  auto issueB = [&](int tt, int d) {
    const char* src = (const char*)wT4 + ((size_t)tt << 15);
    char* dstb = (char*)&ar.m.Bt[d][0] + (wid << 12);
#pragma unroll
    for (int i2 = 0; i2 < 4; ++i2) {
      __builtin_amdgcn_global_load_lds(
          (const __attribute__((address_space(1))) u32*)(src + (wid << 12) + (i2 << 10) + (lane << 4)),
          (__attribute__((address_space(3))) u32*)(dstb + (i2 << 10)),
          16, 0, 0);
    }
  };
  auto packA = [&](int d) {
    u32 outp[8];
#pragma unroll
    for (int e = 0; e < 8; ++e) {
      u32 u00 = (e < 4) ? r00a[e] : r00b[e - 4];
      u32 u01 = (e < 4) ? r01a[e] : r01b[e - 4];
      u32 u10 = (e < 4) ? r10a[e] : r10b[e - 4];
      u32 u11 = (e < 4) ? r11a[e] : r11b[e - 4];
      float lo = w00 * __uint_as_float(u00 << 16);
      lo = fmaf(w01, __uint_as_float(u01 << 16), lo);
      lo = fmaf(w10, __uint_as_float(u10 << 16), lo);
      lo = fmaf(w11, __uint_as_float(u11 << 16), lo);
      float hi = w00 * __uint_as_float(u00 & 0xffff0000u);
      hi = fmaf(w01, __uint_as_float(u01 & 0xffff0000u), hi);
      hi = fmaf(w10, __uint_as_float(u10 & 0xffff0000u), hi);
      hi = fmaf(w11, __uint_as_float(u11 & 0xffff0000u), hi);
      u32 r;
      asm("v_cvt_pk_bf16_f32 %0, %1, %2" : "=v"(r) : "v"(lo), "v"(hi));
      outp[e] = r;
    }
    char* dst = (char*)&ar.m.A[d][0][0] + p_my * 128;
    int b0 = (t & 3) << 5;
    int sw = (p_my & 7) << 4;
    u32x4 t0 = {outp[0], outp[1], outp[2], outp[3]};
    u32x4 t1 = {outp[4], outp[5], outp[6], outp[7]};
    *(u32x4*)(dst + (b0 ^ sw)) = t0;
    *(u32x4*)(dst + ((b0 + 16) ^ sw)) = t1;
  };

  issueA(0);
  issueB(0, 0);
  packA(0);
  __syncthreads();

  const int rbase = wr << 6;
  const int obase = wc << 6;
  int cur = 0;
  for (int tt = 0; tt < 36; ++tt) {
    if (tt < 35) { issueA(tt + 1); issueB(tt + 1, cur ^ 1); }
    __builtin_amdgcn_s_setprio(1);
#pragma unroll
    for (int s = 0; s < 2; ++s) {
      bf16x8 a[4], bb[4];
#pragma unroll
      for (int i = 0; i < 4; ++i) {
        int row = rbase + (i << 4) + (lane & 15);
        int bir = ((s << 6) + ((lane >> 4) << 4)) ^ ((row & 7) << 4);
        a[i] = *(const bf16x8*)((const char*)&ar.m.A[cur][0][0] + row * 128 + bir);
      }
#pragma unroll
      for (int j = 0; j < 4; ++j) {
        int o = obase + (j << 4) + (lane & 15);
        int kb = ((s << 6) + ((lane >> 4) << 4)) ^ ((o & 7) << 4);
        bb[j] = *(const bf16x8*)((const char*)&ar.m.Bt[cur][0] + o * 128 + kb);
      }
#pragma unroll
      for (int i = 0; i < 4; ++i)
#pragma unroll
        for (int j = 0; j < 4; ++j)
          acc[i][j] = __builtin_amdgcn_mfma_f32_16x16x32_bf16(a[i], bb[j], acc[i][j], 0, 0, 0);
    }
    __builtin_amdgcn_s_setprio(0);
    if (tt < 35) packA(cur ^ 1);
    __syncthreads();
    cur ^= 1;
  }

  // --- GroupNorm partial sums (D layout: col=lane&15 -> o, row=(lane>>4)*4+r -> px) ---
#pragma unroll
  for (int j = 0; j < 4; ++j) {
    float s1 = 0.f, s2 = 0.f;
#pragma unroll
    for (int i = 0; i < 4; ++i)
#pragma unroll
      for (int r = 0; r < 4; ++r) {
        float v = acc[i][j][r];
        s1 += v;
        s2 += v * v;
      }
    s1 += __shfl_xor(s1, 1, 64);  s2 += __shfl_xor(s2, 1, 64);
    s1 += __shfl_xor(s1, 2, 64);  s2 += __shfl_xor(s2, 2, 64);
    s1 += __shfl_xor(s1, 4, 64);  s2 += __shfl_xor(s2, 4, 64);
    s1 += __shfl_xor(s1, 16, 64); s2 += __shfl_xor(s2, 16, 64);
    s1 += __shfl_xor(s1, 32, 64); s2 += __shfl_xor(s2, 32, 64);
    if ((lane & 0x37) == 0) {     // lanes 0 and 8: one per 8-channel group
      int g = (obase + (j << 4) + (lane & 15)) >> 3;
      atomicAdd(&stats[((b << 5) + g) * 2 + 0], s1);
      atomicAdd(&stats[((b << 5) + g) * 2 + 1], s2);
    }
  }

  // --- epilogue: acc -> ytile[o][px] bf16 -> y[b][o][px] bf16 ---
#pragma unroll
  for (int i = 0; i < 4; ++i)
#pragma unroll
    for (int j = 0; j < 4; ++j) {
      int o = obase + (j << 4) + (lane & 15);
      int pxr = rbase + (i << 4) + ((lane >> 4) << 2);
      u32 w0, w1;
      asm("v_cvt_pk_bf16_f32 %0, %1, %2" : "=v"(w0) : "v"(acc[i][j][0]), "v"(acc[i][j][1]));
      asm("v_cvt_pk_bf16_f32 %0, %1, %2" : "=v"(w1) : "v"(acc[i][j][2]), "v"(acc[i][j][3]));
      u32x2 wv = {w0, w1};
      *(u32x2*)((char*)ar.ytile + o * 272 + pxr * 2) = wv;
    }
  __syncthreads();
  {
    int o = t >> 1, half = t & 1;
    const char* srcb = (const char*)ar.ytile + o * 272 + (half << 7);
    unsigned short* dst = yb + (((size_t)(b * 256 + o)) << 12) + pxbase + (half << 6);
#pragma unroll
    for (int q = 0; q < 8; ++q)
      *(u32x4*)((char*)dst + (q << 4)) = *(const u32x4*)(srcb + (q << 4));
  }
}

// ---------------------------------------------------------------------------
// K5: GroupNorm finalize + Mish — pure streaming (y bf16 [b][o][px] -> out
// fp32 [b][o][px], identical linear index). grid 2048 x 256, 2 vecs/thread.
// ---------------------------------------------------------------------------
__global__ __launch_bounds__(256) void gn_mish(const unsigned short* __restrict__ yb,
                                               const float* __restrict__ stats,
                                               const float* __restrict__ gamma,
                                               const float* __restrict__ beta,
                                               float* __restrict__ out) {
  int v = blockIdx.x * 512 + threadIdx.x;
#pragma unroll
  for (int it = 0; it < 2; ++it, v += 256) {
    int o = (v >> 9) & 255;
    int b = v >> 17;
    float s1 = stats[((b << 5) + (o >> 3)) * 2 + 0];
    float s2 = stats[((b << 5) + (o >> 3)) * 2 + 1];
    float mean = s1 * (1.f / 32768.f);
    float var = s2 * (1.f / 32768.f) - mean * mean;
    float rstd = rsqrtf(var + 1e-5f);
    float ga = gamma[o] * rstd, be = beta[o] - mean * gamma[o] * rstd;
    u32x4 u = *(const u32x4*)(yb + ((size_t)v << 3));
    float res[8];
#pragma unroll
    for (int e = 0; e < 4; ++e) {
      float va = __uint_as_float(u[e] << 16);
      float vb = __uint_as_float(u[e] & 0xffff0000u);
      float v0 = fmaf(va, ga, be);
      float v1 = fmaf(vb, ga, be);
      float e0 = expf(fminf(v0, 15.f));
      float e1 = expf(fminf(v1, 15.f));
      float n0 = e0 * (e0 + 2.f);
      float n1 = e1 * (e1 + 2.f);
      float m0 = v0 * (n0 / (n0 + 2.f));
      float m1 = v1 * (n1 / (n1 + 2.f));
      if (v0 > 15.f) m0 = v0;
      if (v1 > 15.f) m1 = v1;
      res[2 * e] = m0;
      res[2 * e + 1] = m1;
    }
    f32x4 o0 = {res[0], res[1], res[2], res[3]};
    f32x4 o1 = {res[4], res[5], res[6], res[7]};
    float* dst = out + ((size_t)v << 3);
    *(f32x4*)dst = o0;
    *((f32x4*)dst + 1) = o1;
  }
}

// ---------------------------------------------------------------------------
extern "C" void kernel_launch(void* const* d_in, const int* in_sizes, int n_in,
                              void* d_out, int out_size, void* d_ws, size_t ws_size,
                              hipStream_t stream) {
  const float* x     = (const float*)d_in[0];
  const float* w_off = (const float*)d_in[1];
  const float* b_off = (const float*)d_in[2];
  const float* w_dcn = (const float*)d_in[3];
  const float* gamma = (const float*)d_in[4];
  const float* beta  = (const float*)d_in[5];
  float* out = (float*)d_out;
  char* ws = (char*)d_ws;
  unsigned short* xT   = (unsigned short*)(ws);              // 16,777,216 B (bf16)
  unsigned short* yb   = (unsigned short*)(ws + 16777216);   // 16,777,216 B (bf16)
  float* offs          = (float*)(ws + 33554432);            //  2,359,296 B
  unsigned short* wT4  = (unsigned short*)(ws + 35913728);   //  1,179,648 B
  unsigned short* wOffT= (unsigned short*)(ws + 37093376);   //    147,456 B
  float* stats         = (float*)(ws + 37240832);            //      2,048 B
  prep<<<dim3(2594), dim3(256), 0, stream>>>(w_dcn, w_off, wT4, wOffT, stats);
  transpose_x<<<dim3(2048), dim3(256), 0, stream>>>(x, xT);
  conv_offset_mfma<<<dim3(512), dim3(256), 0, stream>>>(xT, wOffT, offs);
  dcn_main<<<dim3(256), dim3(512), 0, stream>>>(xT, offs, b_off, wT4, yb, stats);
  gn_mish<<<dim3(2048), dim3(256), 0, stream>>>(yb, stats, gamma, beta, out);
}

// Round 5
// 134.042 us; speedup vs baseline: 3.3876x; 1.0346x over previous
//
#include <hip/hip_runtime.h>
#include <hip/hip_bf16.h>
#include <math.h>

typedef __bf16 bf16x8 __attribute__((ext_vector_type(8)));
typedef float f32x4 __attribute__((ext_vector_type(4)));
typedef unsigned int u32;
typedef u32 u32x4 __attribute__((ext_vector_type(4)));
typedef u32 u32x2 __attribute__((ext_vector_type(2)));

// Problem constants: B=8, C=256, H=W=64, O=256, K=9, GN groups=32 (8 ch each)

__device__ inline u32 pack2bf16(float a, float b) {
  u32 ua = __float_as_uint(a);
  u32 ub = __float_as_uint(b);
  ua += 0x7fffu + ((ua >> 16) & 1u);   // RNE
  ub += 0x7fffu + ((ub >> 16) & 1u);
  return (ua >> 16) | (ub & 0xffff0000u);
}

// ---------------------------------------------------------------------------
// K0: prep — pack w_dcn into swizzled bf16 tiles, pack w_off into swizzled
// bf16 tiles (O padded 18->32), zero stats.
// ---------------------------------------------------------------------------
__global__ void prep(const float* __restrict__ w_dcn, const float* __restrict__ w_off,
                     unsigned short* __restrict__ wT4, unsigned short* __restrict__ wOffT,
                     float* __restrict__ stats) {
  size_t id = (size_t)blockIdx.x * 256 + threadIdx.x;
  if (id < 589824) {               // 256 o * 2304 ck
    int o  = (int)(id / 2304);
    int ck = (int)(id % 2304);     // ck = k*256 + c
    int k = ck >> 8, c = ck & 255;
    float v = w_dcn[(size_t)(o * 256 + c) * 9 + k];
    u32 uv = __float_as_uint(v);
    uv += 0x7fffu + ((uv >> 16) & 1u);
    int tile = ck >> 6, kk = ck & 63;
    int lin = o * 128 + kk * 2;
    int swz = lin ^ ((o & 7) << 4);
    *(unsigned short*)((char*)wT4 + (size_t)tile * 32768 + swz) = (unsigned short)(uv >> 16);
  } else if (id < 663552) {        // 36 tiles * 32 o * 64 kk = 73728
    int r = (int)(id - 589824);
    int tile = r >> 11;            // k*4 + cc
    int rr = r & 2047;
    int o = rr >> 6, kk = rr & 63;
    int k = tile >> 2, cc = tile & 3;
    int c = (cc << 6) + kk;
    float v = (o < 18) ? w_off[(size_t)(o * 256 + c) * 9 + k] : 0.f;
    u32 uv = __float_as_uint(v);
    uv += 0x7fffu + ((uv >> 16) & 1u);
    int swz = (o * 128 + kk * 2) ^ ((o & 7) << 4);
    *(unsigned short*)((char*)wOffT + (size_t)tile * 4096 + swz) = (unsigned short)(uv >> 16);
  } else if (id < 664064) {        // zero stats: 512 floats
    stats[id - 663552] = 0.f;
  }
}

// ---------------------------------------------------------------------------
// K1: transpose x [B][C][H][W] -> xT [B][H][W][C] bf16  (channels-last)
// ---------------------------------------------------------------------------
__global__ __launch_bounds__(256) void transpose_x(const float* __restrict__ x,
                                                   unsigned short* __restrict__ xT) {
  __shared__ float tl[64][65];
  int bx = blockIdx.x;
  int b = bx >> 8;
  int y = (bx >> 2) & 63;
  int cb = (bx & 3) << 6;
  int t = threadIdx.x;
  int xi = t & 63, cr = t >> 6;
  size_t base = (((size_t)(b * 256 + cb) * 64 + y) << 6);
#pragma unroll
  for (int rep = 0; rep < 16; ++rep) {
    int cl = rep * 4 + cr;
    tl[cl][xi] = x[base + (size_t)cl * 4096 + xi];
  }
  __syncthreads();
  int xw = t >> 2, c4 = (t & 3) << 4;
  unsigned short* dst = xT + (((size_t)b * 4096) + y * 64 + xw) * 256 + cb + c4;
  u32 pk[8];
#pragma unroll
  for (int e = 0; e < 8; ++e)
    pk[e] = pack2bf16(tl[c4 + 2 * e][xw], tl[c4 + 2 * e + 1][xw]);
  u32x4 v0 = {pk[0], pk[1], pk[2], pk[3]};
  u32x4 v1 = {pk[4], pk[5], pk[6], pk[7]};
  *(u32x4*)dst = v0;
  *((u32x4*)dst + 1) = v1;
}

// ---------------------------------------------------------------------------
// K2: offset conv via MFMA, pipelined: issue loads(t+1) -> MFMA(t) ->
// write(t+1). A: [2][64][64] bf16 XOR-swizzled; B via global_load_lds.
// ---------------------------------------------------------------------------
__global__ __launch_bounds__(256, 2) void conv_offset_mfma(
    const unsigned short* __restrict__ xT, const unsigned short* __restrict__ wOffT,
    float* __restrict__ offs) {
  __shared__ unsigned short A[2][64][64];  // 16KB, byte ^= (row&7)<<4
  __shared__ unsigned short Bo[2][2048];   // 8KB  ([32 o][64 kk], swizzled)
  const int bx = blockIdx.x;
  const int lb = ((bx & 7) << 6) + (bx >> 3);   // XCD x -> image x
  const int b = lb >> 6;
  const int y = lb & 63;
  const int t = threadIdx.x;
  const int lane = t & 63, wid = t >> 6;
  const unsigned short* xTb = xT + ((size_t)b << 20);
  const int p = t >> 2;            // pixel in row (= xx)
  const int q16 = (t & 3) << 4;    // 16-channel sub-block within 64-chunk

  f32x4 acc[2];
  {
    f32x4 z = {0.f, 0.f, 0.f, 0.f};
    acc[0] = z; acc[1] = z;
  }

  u32x4 ra = {0u,0u,0u,0u}, rb = {0u,0u,0u,0u};

  auto issue = [&](int tt, int d) {
    int k = tt >> 2, cc = tt & 3;
    int ky = k / 3, kx = k - ky * 3;
    int ys = y - 1 + ky;
    int xs = p - 1 + kx;
    bool ok = ((unsigned)ys < 64u) && ((unsigned)xs < 64u);
    u32x4 z = {0u,0u,0u,0u};
    ra = z; rb = z;
    if (ok) {
      const unsigned short* s0 = xTb + (size_t)(((ys << 6) + xs) << 8) + (cc << 6) + q16;
      ra = *(const u32x4*)s0;
      rb = *(const u32x4*)(s0 + 8);
    }
    __builtin_amdgcn_global_load_lds(
        (const __attribute__((address_space(1))) u32*)((const char*)wOffT + ((size_t)tt << 12) + (wid << 10) + (lane << 4)),
        (__attribute__((address_space(3))) u32*)((char*)&Bo[d][0] + (wid << 10)),
        16, 0, 0);
  };
  auto writeA = [&](int d) {
    char* dst = (char*)&A[d][0][0] + p * 128;
    int b0 = (t & 3) << 5;
    int sw = (p & 7) << 4;
    *(u32x4*)(dst + (b0 ^ sw)) = ra;
    *(u32x4*)(dst + ((b0 + 16) ^ sw)) = rb;
  };

  issue(0, 0);
  writeA(0);
  __syncthreads();

  int cur = 0;
  for (int tt = 0; tt < 36; ++tt) {
    if (tt < 35) issue(tt + 1, cur ^ 1);
#pragma unroll
    for (int s = 0; s < 2; ++s) {
      int row = (wid << 4) + (lane & 15);
      int bir = ((s << 6) + ((lane >> 4) << 4)) ^ ((row & 7) << 4);
      bf16x8 a = *(const bf16x8*)((const char*)&A[cur][0][0] + row * 128 + bir);
#pragma unroll
      for (int j = 0; j < 2; ++j) {
        int o = (j << 4) + (lane & 15);
        int kb = ((s << 6) + ((lane >> 4) << 4)) ^ ((o & 7) << 4);
        bf16x8 bv = *(const bf16x8*)((const char*)&Bo[cur][0] + o * 128 + kb);
        acc[j] = __builtin_amdgcn_mfma_f32_16x16x32_bf16(a, bv, acc[j], 0, 0, 0);
      }
    }
    if (tt < 35) writeA(cur ^ 1);
    __syncthreads();
    cur ^= 1;
  }

#pragma unroll
  for (int j = 0; j < 2; ++j) {
    int o = (j << 4) + (lane & 15);
    if (o < 18) {
#pragma unroll
      for (int r = 0; r < 4; ++r) {
        int pl = (wid << 4) + ((lane >> 4) << 2) + r;
        offs[((size_t)b * 4096 + (y << 6) + pl) * 18 + o] = acc[j][r];
      }
    }
  }
}

// ---------------------------------------------------------------------------
// K4: main fused kernel — PRODUCER/CONSUMER wave specialization.
// block = 128 px x 256 O, 512 thr: waves 0-3 consumers (wave wc owns
// 128px x 64o, acc[8][4]); waves 4-7 producers (thread = 1px x 32ch:
// sample+pack A, global_load_lds B). Ping-pong dbuf, 1 barrier/step.
// Each SIMD hosts 1 consumer + 1 producer -> producer latency hides under
// the consumer's MFMA pipe time.
// ---------------------------------------------------------------------------
union Arena {
  struct {
    unsigned short A[2][128][64];   // 32,768 B (byte ^= (row&7)<<4)
    unsigned short Bt[2][16384];    // 65,536 B ([256 o][64 kk] swz)
  } m;
  unsigned short ytile[256][136];   // 69,632 B (o-major epilogue buffer)
};

__global__ __launch_bounds__(512, 2) void dcn_main(
    const unsigned short* __restrict__ xT, const float* __restrict__ offs,
    const float* __restrict__ boff, const unsigned short* __restrict__ wT4,
    unsigned short* __restrict__ yb, float* __restrict__ stats) {
  __shared__ Arena ar;
  __shared__ unsigned short poffu[128][9][4];  //  9,216 B
  __shared__ float pw[128][9][4];              // 18,432 B

  const int bx = blockIdx.x;
  const int lb = ((bx & 7) << 5) + (bx >> 3);   // XCD x -> image x
  const int b = lb >> 5;
  const int pxbase = (lb & 31) << 7;            // 128-px group (2 rows)
  const int t = threadIdx.x;
  const int lane = t & 63, wid = t >> 6;
  const bool is_cons = (wid < 4);
  const int obase = (wid & 3) << 6;             // consumer o-block
  const unsigned short* xTb = xT + ((size_t)b << 20);

  // producer mapping: q in [0,256): p_my = q>>1 (px), half = q&1 (32-ch half)
  const int q = ((wid & 3) << 6) + lane;
  const int p_my = q >> 1;
  const int half = q & 1;

  // --- per-(pixel,k) sampling params into LDS (all waves) ---
  for (int idx = t; idx < 1152; idx += 512) {
    int p = idx / 9, k = idx - p * 9;
    int pxg = pxbase + p;
    int yy = pxg >> 6, xx = pxg & 63;
    const float* op = offs + ((size_t)b * 4096 + pxg) * 18 + k * 2;
    int kyi = k / 3, kxi = k - kyi * 3;
    float py = op[0] + boff[k * 2] + (float)(yy - 1 + kyi);
    float pxf = op[1] + boff[k * 2 + 1] + (float)(xx - 1 + kxi);
    float fy = floorf(py), fx = floorf(pxf);
    float dy = py - fy, dx = pxf - fx;
    int y0 = (int)fy, x0 = (int)fx;
    int y1 = y0 + 1, x1 = x0 + 1;
    float vy0 = ((unsigned)y0 < 64u) ? 1.f : 0.f;
    float vy1 = ((unsigned)y1 < 64u) ? 1.f : 0.f;
    float vx0 = ((unsigned)x0 < 64u) ? 1.f : 0.f;
    float vx1 = ((unsigned)x1 < 64u) ? 1.f : 0.f;
    int y0c = min(max(y0, 0), 63), y1c = min(max(y1, 0), 63);
    int x0c = min(max(x0, 0), 63), x1c = min(max(x1, 0), 63);
    poffu[p][k][0] = (unsigned short)((y0c << 6) + x0c);
    poffu[p][k][1] = (unsigned short)((y0c << 6) + x1c);
    poffu[p][k][2] = (unsigned short)((y1c << 6) + x0c);
    poffu[p][k][3] = (unsigned short)((y1c << 6) + x1c);
    pw[p][k][0] = (1.f - dy) * (1.f - dx) * vy0 * vx0;
    pw[p][k][1] = (1.f - dy) * dx * vy0 * vx1;
    pw[p][k][2] = dy * (1.f - dx) * vy1 * vx0;
    pw[p][k][3] = dy * dx * vy1 * vx1;
  }

  f32x4 acc[8][4];
#pragma unroll
  for (int i = 0; i < 8; ++i)
#pragma unroll
    for (int j = 0; j < 4; ++j) {
      f32x4 z = {0.f, 0.f, 0.f, 0.f};
      acc[i][j] = z;
    }

  __syncthreads();                 // params ready

  // producer: sample+pack A(nt) and stage B(nt) into buffer d
  auto stage = [&](int nt, int d) {
    int k = nt >> 2, cc = nt & 3;
    int cb = (cc << 6) + (half << 5);
    const unsigned short* s0 = xTb + ((int)poffu[p_my][k][0] << 8) + cb;
    const unsigned short* s1 = xTb + ((int)poffu[p_my][k][1] << 8) + cb;
    const unsigned short* s2 = xTb + ((int)poffu[p_my][k][2] << 8) + cb;
    const unsigned short* s3 = xTb + ((int)poffu[p_my][k][3] << 8) + cb;
    u32x4 r0[4], r1[4], r2[4], r3[4];
#pragma unroll
    for (int v = 0; v < 4; ++v) {
      r0[v] = *(const u32x4*)(s0 + (v << 3));
      r1[v] = *(const u32x4*)(s1 + (v << 3));
      r2[v] = *(const u32x4*)(s2 + (v << 3));
      r3[v] = *(const u32x4*)(s3 + (v << 3));
    }
    // B: async global->LDS, 8KB per producer wave (linear, pre-swizzled src)
    {
      const char* src = (const char*)wT4 + ((size_t)nt << 15) + ((wid & 3) << 13);
      char* dstb = (char*)&ar.m.Bt[d][0] + ((wid & 3) << 13);
#pragma unroll
      for (int i2 = 0; i2 < 8; ++i2) {
        __builtin_amdgcn_global_load_lds(
            (const __attribute__((address_space(1))) u32*)(src + (i2 << 10) + (lane << 4)),
            (__attribute__((address_space(3))) u32*)(dstb + (i2 << 10)),
            16, 0, 0);
      }
    }
    float w0 = pw[p_my][k][0], w1 = pw[p_my][k][1];
    float w2 = pw[p_my][k][2], w3 = pw[p_my][k][3];
    char* dst = (char*)&ar.m.A[d][0][0] + p_my * 128;
    int sw = (p_my & 7) << 4;
#pragma unroll
    for (int v = 0; v < 4; ++v) {
      u32 o4[4];
#pragma unroll
      for (int e = 0; e < 4; ++e) {
        u32 u0 = r0[v][e], u1 = r1[v][e], u2 = r2[v][e], u3 = r3[v][e];
        float lo = w0 * __uint_as_float(u0 << 16);
        lo = fmaf(w1, __uint_as_float(u1 << 16), lo);
        lo = fmaf(w2, __uint_as_float(u2 << 16), lo);
        lo = fmaf(w3, __uint_as_float(u3 << 16), lo);
        float hi = w0 * __uint_as_float(u0 & 0xffff0000u);
        hi = fmaf(w1, __uint_as_float(u1 & 0xffff0000u), hi);
        hi = fmaf(w2, __uint_as_float(u2 & 0xffff0000u), hi);
        hi = fmaf(w3, __uint_as_float(u3 & 0xffff0000u), hi);
        u32 r;
        asm("v_cvt_pk_bf16_f32 %0, %1, %2" : "=v"(r) : "v"(lo), "v"(hi));
        o4[e] = r;
      }
      u32x4 ov = {o4[0], o4[1], o4[2], o4[3]};
      *(u32x4*)(dst + (((half << 6) + (v << 4)) ^ sw)) = ov;
    }
  };

  if (!is_cons) stage(0, 0);
  __syncthreads();

  int cur = 0;
  for (int tt = 0; tt < 36; ++tt) {
    if (is_cons) {
      const char* Abase = (const char*)&ar.m.A[cur][0][0];
      const char* Bbase = (const char*)&ar.m.Bt[cur][0];
      __builtin_amdgcn_s_setprio(1);
#pragma unroll
      for (int s = 0; s < 2; ++s) {
        int kx = (s << 6) + ((lane >> 4) << 4);
        int swl = (lane & 7) << 4;
        bf16x8 a[8], bb[4];
#pragma unroll
        for (int i = 0; i < 8; ++i)
          a[i] = *(const bf16x8*)(Abase + ((i << 4) + (lane & 15)) * 128 + (kx ^ swl));
#pragma unroll
        for (int j = 0; j < 4; ++j)
          bb[j] = *(const bf16x8*)(Bbase + (obase + (j << 4) + (lane & 15)) * 128 + (kx ^ swl));
#pragma unroll
        for (int i = 0; i < 8; ++i)
#pragma unroll
          for (int j = 0; j < 4; ++j)
            acc[i][j] = __builtin_amdgcn_mfma_f32_16x16x32_bf16(a[i], bb[j], acc[i][j], 0, 0, 0);
      }
      __builtin_amdgcn_s_setprio(0);
    } else {
      if (tt < 35) stage(tt + 1, cur ^ 1);
    }
    __syncthreads();
    cur ^= 1;
  }

  if (is_cons) {
    // --- GroupNorm partial sums ---
#pragma unroll
    for (int j = 0; j < 4; ++j) {
      float s1 = 0.f, s2 = 0.f;
#pragma unroll
      for (int i = 0; i < 8; ++i)
#pragma unroll
        for (int r = 0; r < 4; ++r) {
          float v = acc[i][j][r];
          s1 += v;
          s2 += v * v;
        }
      s1 += __shfl_xor(s1, 1, 64);  s2 += __shfl_xor(s2, 1, 64);
      s1 += __shfl_xor(s1, 2, 64);  s2 += __shfl_xor(s2, 2, 64);
      s1 += __shfl_xor(s1, 4, 64);  s2 += __shfl_xor(s2, 4, 64);
      s1 += __shfl_xor(s1, 16, 64); s2 += __shfl_xor(s2, 16, 64);
      s1 += __shfl_xor(s1, 32, 64); s2 += __shfl_xor(s2, 32, 64);
      if ((lane & 0x37) == 0) {     // lanes 0 and 8: one per 8-channel group
        int g = (obase + (j << 4) + (lane & 15)) >> 3;
        atomicAdd(&stats[((b << 5) + g) * 2 + 0], s1);
        atomicAdd(&stats[((b << 5) + g) * 2 + 1], s2);
      }
    }
    // --- acc -> ytile[o][px] bf16 ---
#pragma unroll
    for (int i = 0; i < 8; ++i)
#pragma unroll
      for (int j = 0; j < 4; ++j) {
        int o = obase + (j << 4) + (lane & 15);
        int pxr = (i << 4) + ((lane >> 4) << 2);
        u32 w0, w1;
        asm("v_cvt_pk_bf16_f32 %0, %1, %2" : "=v"(w0) : "v"(acc[i][j][0]), "v"(acc[i][j][1]));
        asm("v_cvt_pk_bf16_f32 %0, %1, %2" : "=v"(w1) : "v"(acc[i][j][2]), "v"(acc[i][j][3]));
        u32x2 wv = {w0, w1};
        *(u32x2*)((char*)ar.ytile + o * 272 + pxr * 2) = wv;
      }
  }
  __syncthreads();
  {
    int o = t >> 1, hf = t & 1;
    const char* srcb = (const char*)ar.ytile + o * 272 + (hf << 7);
    unsigned short* dst = yb + (((size_t)(b * 256 + o)) << 12) + pxbase + (hf << 6);
#pragma unroll
    for (int qq = 0; qq < 8; ++qq)
      *(u32x4*)((char*)dst + (qq << 4)) = *(const u32x4*)(srcb + (qq << 4));
  }
}

// ---------------------------------------------------------------------------
// K5: GroupNorm finalize + Mish — pure streaming.
// ---------------------------------------------------------------------------
__global__ __launch_bounds__(256) void gn_mish(const unsigned short* __restrict__ yb,
                                               const float* __restrict__ stats,
                                               const float* __restrict__ gamma,
                                               const float* __restrict__ beta,
                                               float* __restrict__ out) {
  int v = blockIdx.x * 512 + threadIdx.x;
#pragma unroll
  for (int it = 0; it < 2; ++it, v += 256) {
    int o = (v >> 9) & 255;
    int b = v >> 17;
    float s1 = stats[((b << 5) + (o >> 3)) * 2 + 0];
    float s2 = stats[((b << 5) + (o >> 3)) * 2 + 1];
    float mean = s1 * (1.f / 32768.f);
    float var = s2 * (1.f / 32768.f) - mean * mean;
    float rstd = rsqrtf(var + 1e-5f);
    float ga = gamma[o] * rstd, be = beta[o] - mean * gamma[o] * rstd;
    u32x4 u = *(const u32x4*)(yb + ((size_t)v << 3));
    float res[8];
#pragma unroll
    for (int e = 0; e < 4; ++e) {
      float va = __uint_as_float(u[e] << 16);
      float vb = __uint_as_float(u[e] & 0xffff0000u);
      float v0 = fmaf(va, ga, be);
      float v1 = fmaf(vb, ga, be);
      float e0 = expf(fminf(v0, 15.f));
      float e1 = expf(fminf(v1, 15.f));
      float n0 = e0 * (e0 + 2.f);
      float n1 = e1 * (e1 + 2.f);
      float m0 = v0 * (n0 / (n0 + 2.f));
      float m1 = v1 * (n1 / (n1 + 2.f));
      if (v0 > 15.f) m0 = v0;
      if (v1 > 15.f) m1 = v1;
      res[2 * e] = m0;
      res[2 * e + 1] = m1;
    }
    f32x4 o0 = {res[0], res[1], res[2], res[3]};
    f32x4 o1 = {res[4], res[5], res[6], res[7]};
    float* dst = out + ((size_t)v << 3);
    *(f32x4*)dst = o0;
    *((f32x4*)dst + 1) = o1;
  }
}

// ---------------------------------------------------------------------------
extern "C" void kernel_launch(void* const* d_in, const int* in_sizes, int n_in,
                              void* d_out, int out_size, void* d_ws, size_t ws_size,
                              hipStream_t stream) {
  const float* x     = (const float*)d_in[0];
  const float* w_off = (const float*)d_in[1];
  const float* b_off = (const float*)d_in[2];
  const float* w_dcn = (const float*)d_in[3];
  const float* gamma = (const float*)d_in[4];
  const float* beta  = (const float*)d_in[5];
  float* out = (float*)d_out;
  char* ws = (char*)d_ws;
  unsigned short* xT   = (unsigned short*)(ws);              // 16,777,216 B (bf16)
  unsigned short* yb   = (unsigned short*)(ws + 16777216);   // 16,777,216 B (bf16)
  float* offs          = (float*)(ws + 33554432);            //  2,359,296 B
  unsigned short* wT4  = (unsigned short*)(ws + 35913728);   //  1,179,648 B
  unsigned short* wOffT= (unsigned short*)(ws + 37093376);   //    147,456 B
  float* stats         = (float*)(ws + 37240832);            //      2,048 B
  prep<<<dim3(2594), dim3(256), 0, stream>>>(w_dcn, w_off, wT4, wOffT, stats);
  transpose_x<<<dim3(2048), dim3(256), 0, stream>>>(x, xT);
  conv_offset_mfma<<<dim3(512), dim3(256), 0, stream>>>(xT, wOffT, offs);
  dcn_main<<<dim3(256), dim3(512), 0, stream>>>(xT, offs, b_off, wT4, yb, stats);
  gn_mish<<<dim3(2048), dim3(256), 0, stream>>>(yb, stats, gamma, beta, out);
}